// Round 6
// baseline (840.424 us; speedup 1.0000x reference)
//
#include <hip/hip_runtime.h>
#include <cstdint>
#include <cstddef>

// MixedAttention: qkv GEMM -> {neighborhood attn | flash self attn} -> proj GEMM
// Inputs fp32, output fp32. Flash v2: 4-wave blocks, shared conflict-free K/V
// staging, 4-way ILP-split QK accumulators. Split-K partials in d_out (dead
// until gemm2) + (m,l) in ws; combine merges into attn buffer.

#define DIMC 512
#define HEADS 8
#define HD 32
#define KSZ 7
#define HH 48
#define WW 48
#define BB 2
#define NPIX (HH * WW)         // 2304
#define ROWS (BB * NPIX)       // 4608
#define C3 (3 * DIMC)          // 1536
#define TK 32                  // key tile
#define KSPLIT 4
#define KCHUNK (NPIX / KSPLIT) // 576
#define NTILES (KCHUNK / TK)   // 18
#define QB 256                 // queries per block (64 per wave)
#define NQBLK (NPIX / QB)      // 9

static __device__ __forceinline__ float bf2f(uint32_t u) {
    return __builtin_bit_cast(float, u << 16);
}
static __device__ __forceinline__ uint16_t f2bf(float f) {
    uint32_t x = __builtin_bit_cast(uint32_t, f);
    uint32_t r = x + 0x7fffu + ((x >> 16) & 1u);
    return (uint16_t)(r >> 16);
}

// ---------------- GEMM: C[M,N] = A[M,K] @ B[K,N] + bias[N], fp32
template<int BM, int BN, int BK>
__global__ __launch_bounds__(256)
void gemm_bias(const float* __restrict__ A, const float* __restrict__ Bm,
               const float* __restrict__ bias, float* __restrict__ C,
               int M, int N, int K)
{
    __shared__ float As[BK][BM + 4];
    __shared__ float Bs[BK][BN + 4];
    const int tid = threadIdx.x;
    const int tx = tid & 15, ty = tid >> 4;
    const int m0 = blockIdx.y * BM, n0 = blockIdx.x * BN;
    float acc[4][4] = {};
    for (int k0 = 0; k0 < K; k0 += BK) {
        {
            const int m = tid >> 2, kq = (tid & 3) * 4;
            const float4 a4 = *reinterpret_cast<const float4*>(A + (size_t)(m0 + m) * K + k0 + kq);
            As[kq + 0][m] = a4.x;
            As[kq + 1][m] = a4.y;
            As[kq + 2][m] = a4.z;
            As[kq + 3][m] = a4.w;
        }
        {
            const int kb = tid >> 4, nq = (tid & 15) * 4;
            const float4 b4 = *reinterpret_cast<const float4*>(Bm + (size_t)(k0 + kb) * N + n0 + nq);
            Bs[kb][nq + 0] = b4.x;
            Bs[kb][nq + 1] = b4.y;
            Bs[kb][nq + 2] = b4.z;
            Bs[kb][nq + 3] = b4.w;
        }
        __syncthreads();
        #pragma unroll
        for (int kk = 0; kk < BK; ++kk) {
            const float4 av = *reinterpret_cast<const float4*>(&As[kk][ty * 4]);
            const float4 bv = *reinterpret_cast<const float4*>(&Bs[kk][tx * 4]);
            const float a_[4] = {av.x, av.y, av.z, av.w};
            const float b_[4] = {bv.x, bv.y, bv.z, bv.w};
            #pragma unroll
            for (int i = 0; i < 4; ++i)
                #pragma unroll
                for (int j = 0; j < 4; ++j)
                    acc[i][j] = fmaf(a_[i], b_[j], acc[i][j]);
        }
        __syncthreads();
    }
    float bv[4];
    #pragma unroll
    for (int j = 0; j < 4; ++j) bv[j] = bias[n0 + tx * 4 + j];
    #pragma unroll
    for (int i = 0; i < 4; ++i) {
        const size_t roff = (size_t)(m0 + ty * 4 + i) * N + n0 + tx * 4;
        float4 st;
        st.x = acc[i][0] + bv[0];
        st.y = acc[i][1] + bv[1];
        st.z = acc[i][2] + bv[2];
        st.w = acc[i][3] + bv[3];
        *reinterpret_cast<float4*>(C + roff) = st;
    }
}

// ---------------- Neighborhood attention (unchanged)
__global__ __launch_bounds__(256)
void na_attn(const float* __restrict__ qkv, const float* __restrict__ rpb,
             float* __restrict__ attn)
{
    const int wave = threadIdx.x >> 6, lane = threadIdx.x & 63;
    const int item = blockIdx.x * 4 + wave;
    const int pix = item % NPIX;
    const int bh = item / NPIX;
    const int h = bh & (HEADS - 1);
    const int b = bh >> 3;
    const int i = pix / WW, j = pix % WW;
    const int ni = min(max(i - 3, 0), HH - KSZ);
    const int nj = min(max(j - 3, 0), WW - KSZ);
    const int pi = 3 + max(3 - i, 0) + ((i + 3 >= HH) ? (HH - i - 4) : 0);
    const int pj = 3 + max(3 - j, 0) + ((j + 3 >= WW) ? (WW - j - 4) : 0);
    const float scale = 0.17677669529663687f;

    __shared__ float qsm[4][HD];
    __shared__ float aw[4][64];
    __shared__ int   rsm[4][64];

    const size_t rowbase = (size_t)b * NPIX;
    if (lane < HD)
        qsm[wave][lane] = qkv[(rowbase + pix) * C3 + h * HD + lane] * scale;
    __syncthreads();

    float sc = -1e30f;
    int nrow = 0;
    if (lane < KSZ * KSZ) {
        const int ki = lane / KSZ, kj = lane % KSZ;
        nrow = (ni + ki) * WW + (nj + kj);
        const float* kp = qkv + (rowbase + nrow) * C3 + 256 + h * HD;
        float acc = 0.f;
        #pragma unroll
        for (int d = 0; d < HD; d += 4) {
            const float4 kv = *reinterpret_cast<const float4*>(kp + d);
            acc = fmaf(qsm[wave][d + 0], kv.x, acc);
            acc = fmaf(qsm[wave][d + 1], kv.y, acc);
            acc = fmaf(qsm[wave][d + 2], kv.z, acc);
            acc = fmaf(qsm[wave][d + 3], kv.w, acc);
        }
        sc = acc + rpb[h * 169 + (pi + ki) * 13 + (pj + kj)];
    }
    float m = sc;
    #pragma unroll
    for (int off = 32; off > 0; off >>= 1) m = fmaxf(m, __shfl_xor(m, off));
    float e = (lane < KSZ * KSZ) ? __expf(sc - m) : 0.f;
    float s = e;
    #pragma unroll
    for (int off = 32; off > 0; off >>= 1) s += __shfl_xor(s, off);
    aw[wave][lane] = e / s;
    rsm[wave][lane] = nrow;
    __syncthreads();

    if (lane < HD) {
        float acc = 0.f;
        for (int l = 0; l < KSZ * KSZ; ++l) {
            const float a = aw[wave][l];
            const size_t r = rowbase + rsm[wave][l];
            acc = fmaf(a, qkv[r * C3 + 512 + h * HD + lane], acc);
        }
        attn[(rowbase + pix) * DIMC + h * HD + lane] = acc;
    }
}

// ---------------- Flash self-attention v2. 256-thread blocks (4 waves).
// Each lane owns one query; block stages K/V tile (conflict-free flat layout);
// QK uses 4 independent accumulator chains for ILP.
__global__ __launch_bounds__(256)
void self_attn_flash(const float* __restrict__ qkv,
                     uint16_t* __restrict__ po, float2* __restrict__ pml)
{
    const int tid = threadIdx.x;
    const int lane = tid & 63, wv = tid >> 6;
    const int bid = blockIdx.x;               // [bh][qblk][split]
    const int split = bid & (KSPLIT - 1);
    const int qblk = (bid >> 2) % NQBLK;
    const int bh = bid / (KSPLIT * NQBLK);
    const int h = bh & (HEADS - 1);
    const int b = bh >> 3;
    const int q = qblk * QB + wv * 64 + lane;
    const size_t rowbase = (size_t)b * NPIX;
    const float scale = 0.17677669529663687f;

    __shared__ float4 Ks[TK * 8];   // flat: slot fi=j*8+c; writes by tid -> conflict-free
    __shared__ float4 Vs[TK * 8];

    float4 qf[8];
    {
        const float* qp = qkv + (rowbase + q) * C3 + 768 + h * HD;
        #pragma unroll
        for (int c = 0; c < 8; ++c) {
            float4 v = *reinterpret_cast<const float4*>(qp + c * 4);
            v.x *= scale; v.y *= scale; v.z *= scale; v.w *= scale;
            qf[c] = v;
        }
    }

    float m = -1e30f, l = 0.f;
    float4 of[8];
    #pragma unroll
    for (int c = 0; c < 8; ++c) of[c] = make_float4(0.f, 0.f, 0.f, 0.f);

    int k0 = split * KCHUNK;
    for (int t = 0; t < NTILES; ++t, k0 += TK) {
        __syncthreads();
        {   // one float4 of K and V per thread; lanes 0..7 span banks 0..31
            const int r = tid >> 3, c = tid & 7;
            const float* kp = qkv + (rowbase + k0 + r) * C3 + 1024 + h * HD + c * 4;
            Ks[tid] = *reinterpret_cast<const float4*>(kp);
            Vs[tid] = *reinterpret_cast<const float4*>(kp + 256);  // V at 1280
        }
        __syncthreads();

        float s[TK];
        float tmax = -1e30f;
        #pragma unroll
        for (int j = 0; j < TK; ++j) {
            float a0 = 0.f, a1 = 0.f, a2 = 0.f, a3 = 0.f;   // 4 independent chains
            #pragma unroll
            for (int c = 0; c < 8; c += 4) {
                const float4 k0v = Ks[j * 8 + c + 0];
                const float4 k1v = Ks[j * 8 + c + 1];
                const float4 k2v = Ks[j * 8 + c + 2];
                const float4 k3v = Ks[j * 8 + c + 3];
                a0 = fmaf(qf[c + 0].x, k0v.x, a0); a0 = fmaf(qf[c + 0].y, k0v.y, a0);
                a0 = fmaf(qf[c + 0].z, k0v.z, a0); a0 = fmaf(qf[c + 0].w, k0v.w, a0);
                a1 = fmaf(qf[c + 1].x, k1v.x, a1); a1 = fmaf(qf[c + 1].y, k1v.y, a1);
                a1 = fmaf(qf[c + 1].z, k1v.z, a1); a1 = fmaf(qf[c + 1].w, k1v.w, a1);
                a2 = fmaf(qf[c + 2].x, k2v.x, a2); a2 = fmaf(qf[c + 2].y, k2v.y, a2);
                a2 = fmaf(qf[c + 2].z, k2v.z, a2); a2 = fmaf(qf[c + 2].w, k2v.w, a2);
                a3 = fmaf(qf[c + 3].x, k3v.x, a3); a3 = fmaf(qf[c + 3].y, k3v.y, a3);
                a3 = fmaf(qf[c + 3].z, k3v.z, a3); a3 = fmaf(qf[c + 3].w, k3v.w, a3);
            }
            const float acc = (a0 + a1) + (a2 + a3);
            s[j] = acc;
            tmax = fmaxf(tmax, acc);
        }
        const float newm = fmaxf(m, tmax);
        const float corr = __expf(m - newm);   // first tile: exp(-1e30)=0
        l *= corr;
        #pragma unroll
        for (int c = 0; c < 8; ++c) {
            of[c].x *= corr; of[c].y *= corr; of[c].z *= corr; of[c].w *= corr;
        }
        m = newm;
        #pragma unroll
        for (int j = 0; j < TK; ++j) {
            const float p = __expf(s[j] - m);
            l += p;
            #pragma unroll
            for (int c = 0; c < 8; ++c) {
                const float4 vv = Vs[j * 8 + c];
                of[c].x = fmaf(p, vv.x, of[c].x);
                of[c].y = fmaf(p, vv.y, of[c].y);
                of[c].z = fmaf(p, vv.z, of[c].z);
                of[c].w = fmaf(p, vv.w, of[c].w);
            }
        }
    }

    // normalize per split, store bf16 partial + (m,l)
    const float invl = 1.f / l;
    const size_t item = ((size_t)split * 16 + bh) * NPIX + q;
    uint32_t packed[16];
    #pragma unroll
    for (int c = 0; c < 8; ++c) {
        packed[c * 2 + 0] = (uint32_t)f2bf(of[c].x * invl) | ((uint32_t)f2bf(of[c].y * invl) << 16);
        packed[c * 2 + 1] = (uint32_t)f2bf(of[c].z * invl) | ((uint32_t)f2bf(of[c].w * invl) << 16);
    }
    uint32_t* dst = reinterpret_cast<uint32_t*>(po + item * HD);
    #pragma unroll
    for (int w = 0; w < 4; ++w) {
        uint4 st;
        st.x = packed[w * 4 + 0]; st.y = packed[w * 4 + 1];
        st.z = packed[w * 4 + 2]; st.w = packed[w * 4 + 3];
        *reinterpret_cast<uint4*>(dst + w * 4) = st;
    }
    pml[item] = make_float2(m, l);
}

// ---------------- Combine split-K partials -> attn[:, 256:512)
__global__ __launch_bounds__(256)
void self_attn_combine(const uint16_t* __restrict__ po, const float2* __restrict__ pml,
                       float* __restrict__ attn)
{
    const int idx = blockIdx.x * 256 + threadIdx.x;   // 16*2304*32
    const int d = idx & (HD - 1);
    const int q = (idx >> 5) % NPIX;
    const int bh = idx / (HD * NPIX);
    const int h = bh & (HEADS - 1);
    const int b = bh >> 3;

    float2 ml[KSPLIT];
    float M = -1e30f;
    #pragma unroll
    for (int s = 0; s < KSPLIT; ++s) {
        ml[s] = pml[((size_t)s * 16 + bh) * NPIX + q];
        M = fmaxf(M, ml[s].x);
    }
    float num = 0.f, den = 0.f;
    #pragma unroll
    for (int s = 0; s < KSPLIT; ++s) {
        const float w = __expf(ml[s].x - M) * ml[s].y;
        const float o = bf2f((uint32_t)po[(((size_t)s * 16 + bh) * NPIX + q) * HD + d]);
        num = fmaf(w, o, num);
        den += w;
    }
    attn[((size_t)b * NPIX + q) * DIMC + 256 + h * HD + d] = num / den;
}

extern "C" void kernel_launch(void* const* d_in, const int* in_sizes, int n_in,
                              void* d_out, int out_size, void* d_ws, size_t ws_size,
                              hipStream_t stream)
{
    const float* x     = (const float*)d_in[0];
    const float* Wqkv  = (const float*)d_in[1];
    const float* bqkv  = (const float*)d_in[2];
    const float* rpb   = (const float*)d_in[3];
    const float* Wproj = (const float*)d_in[4];
    const float* bproj = (const float*)d_in[5];

    float* qkv  = (float*)d_ws;                           // ROWS x C3 fp32   (28.3 MB)
    float* attn = qkv + (size_t)ROWS * C3;                // ROWS x DIMC fp32 ( 9.4 MB)
    float2* pml = (float2*)(attn + (size_t)ROWS * DIMC);  // KSPLIT*16*NPIX   ( 1.2 MB)
    uint16_t* po = (uint16_t*)d_out;                      // partial bf16 scratch, dead after combine

    const dim3 blk(256);
    gemm_bias<64, 64, 16><<<dim3(C3 / 64, ROWS / 64), blk, 0, stream>>>(
        x, Wqkv, bqkv, qkv, ROWS, C3, DIMC);
    na_attn<<<dim3((BB * HEADS * NPIX) / 4), blk, 0, stream>>>(qkv, rpb, attn);
    self_attn_flash<<<dim3(16 * NQBLK * KSPLIT), blk, 0, stream>>>(qkv, po, pml);
    self_attn_combine<<<dim3((16 * NPIX * HD) / 256), blk, 0, stream>>>(po, pml, attn);
    gemm_bias<64, 64, 16><<<dim3(DIMC / 64, ROWS / 64), blk, 0, stream>>>(
        attn, Wproj, bproj, (float*)d_out, ROWS, DIMC, DIMC);
}

// Round 7
// 270.029 us; speedup vs baseline: 3.1124x; 3.1124x over previous
//
#include <hip/hip_runtime.h>
#include <cstdint>
#include <cstddef>

// MixedAttention: qkv GEMM -> {neighborhood attn | MFMA flash self attn} -> proj GEMM
// Inputs fp32, output fp32. Flash v3: mfma_f32_16x16x32_bf16, swapped QK^T,
// in-register softmax, shfl-based P repack, transposed-V PV, split-K combine.

#define DIMC 512
#define HEADS 8
#define HD 32
#define KSZ 7
#define HH 48
#define WW 48
#define BB 2
#define NPIX (HH * WW)         // 2304
#define ROWS (BB * NPIX)       // 4608
#define C3 (3 * DIMC)          // 1536
#define TK 32                  // key tile
#define KSPLIT 4
#define KCHUNK (NPIX / KSPLIT) // 576
#define NTILES (KCHUNK / TK)   // 18
#define QB 64                  // queries per block (16 per wave)
#define NQBLK (NPIX / QB)      // 36
#define ROWE 40                // LDS tile row stride in bf16 elems (80B: 2-way banks)

typedef __attribute__((ext_vector_type(8))) short short8;
typedef __attribute__((ext_vector_type(4))) float f32x4;
union frag8 { short8 s; uint32_t u[4]; };

static __device__ __forceinline__ float bf2f(uint32_t u) {
    return __builtin_bit_cast(float, u << 16);
}
static __device__ __forceinline__ uint16_t f2bf(float f) {
    uint32_t x = __builtin_bit_cast(uint32_t, f);
    uint32_t r = x + 0x7fffu + ((x >> 16) & 1u);
    return (uint16_t)(r >> 16);
}
static __device__ __forceinline__ uint32_t cvtpk(float lo, float hi) {
    uint32_t r;
    asm("v_cvt_pk_bf16_f32 %0, %1, %2" : "=v"(r) : "v"(lo), "v"(hi));
    return r;
}

// ---------------- GEMM: C[M,N] = A[M,K] @ B[K,N] + bias[N], fp32 (unchanged)
template<int BM, int BN, int BK>
__global__ __launch_bounds__(256)
void gemm_bias(const float* __restrict__ A, const float* __restrict__ Bm,
               const float* __restrict__ bias, float* __restrict__ C,
               int M, int N, int K)
{
    __shared__ float As[BK][BM + 4];
    __shared__ float Bs[BK][BN + 4];
    const int tid = threadIdx.x;
    const int tx = tid & 15, ty = tid >> 4;
    const int m0 = blockIdx.y * BM, n0 = blockIdx.x * BN;
    float acc[4][4] = {};
    for (int k0 = 0; k0 < K; k0 += BK) {
        {
            const int m = tid >> 2, kq = (tid & 3) * 4;
            const float4 a4 = *reinterpret_cast<const float4*>(A + (size_t)(m0 + m) * K + k0 + kq);
            As[kq + 0][m] = a4.x;
            As[kq + 1][m] = a4.y;
            As[kq + 2][m] = a4.z;
            As[kq + 3][m] = a4.w;
        }
        {
            const int kb = tid >> 4, nq = (tid & 15) * 4;
            const float4 b4 = *reinterpret_cast<const float4*>(Bm + (size_t)(k0 + kb) * N + n0 + nq);
            Bs[kb][nq + 0] = b4.x;
            Bs[kb][nq + 1] = b4.y;
            Bs[kb][nq + 2] = b4.z;
            Bs[kb][nq + 3] = b4.w;
        }
        __syncthreads();
        #pragma unroll
        for (int kk = 0; kk < BK; ++kk) {
            const float4 av = *reinterpret_cast<const float4*>(&As[kk][ty * 4]);
            const float4 bv = *reinterpret_cast<const float4*>(&Bs[kk][tx * 4]);
            const float a_[4] = {av.x, av.y, av.z, av.w};
            const float b_[4] = {bv.x, bv.y, bv.z, bv.w};
            #pragma unroll
            for (int i = 0; i < 4; ++i)
                #pragma unroll
                for (int j = 0; j < 4; ++j)
                    acc[i][j] = fmaf(a_[i], b_[j], acc[i][j]);
        }
        __syncthreads();
    }
    float bv[4];
    #pragma unroll
    for (int j = 0; j < 4; ++j) bv[j] = bias[n0 + tx * 4 + j];
    #pragma unroll
    for (int i = 0; i < 4; ++i) {
        const size_t roff = (size_t)(m0 + ty * 4 + i) * N + n0 + tx * 4;
        float4 st;
        st.x = acc[i][0] + bv[0];
        st.y = acc[i][1] + bv[1];
        st.z = acc[i][2] + bv[2];
        st.w = acc[i][3] + bv[3];
        *reinterpret_cast<float4*>(C + roff) = st;
    }
}

// ---------------- Neighborhood attention (unchanged)
__global__ __launch_bounds__(256)
void na_attn(const float* __restrict__ qkv, const float* __restrict__ rpb,
             float* __restrict__ attn)
{
    const int wave = threadIdx.x >> 6, lane = threadIdx.x & 63;
    const int item = blockIdx.x * 4 + wave;
    const int pix = item % NPIX;
    const int bh = item / NPIX;
    const int h = bh & (HEADS - 1);
    const int b = bh >> 3;
    const int i = pix / WW, j = pix % WW;
    const int ni = min(max(i - 3, 0), HH - KSZ);
    const int nj = min(max(j - 3, 0), WW - KSZ);
    const int pi = 3 + max(3 - i, 0) + ((i + 3 >= HH) ? (HH - i - 4) : 0);
    const int pj = 3 + max(3 - j, 0) + ((j + 3 >= WW) ? (WW - j - 4) : 0);
    const float scale = 0.17677669529663687f;

    __shared__ float qsm[4][HD];
    __shared__ float aw[4][64];
    __shared__ int   rsm[4][64];

    const size_t rowbase = (size_t)b * NPIX;
    if (lane < HD)
        qsm[wave][lane] = qkv[(rowbase + pix) * C3 + h * HD + lane] * scale;
    __syncthreads();

    float sc = -1e30f;
    int nrow = 0;
    if (lane < KSZ * KSZ) {
        const int ki = lane / KSZ, kj = lane % KSZ;
        nrow = (ni + ki) * WW + (nj + kj);
        const float* kp = qkv + (rowbase + nrow) * C3 + 256 + h * HD;
        float acc = 0.f;
        #pragma unroll
        for (int d = 0; d < HD; d += 4) {
            const float4 kv = *reinterpret_cast<const float4*>(kp + d);
            acc = fmaf(qsm[wave][d + 0], kv.x, acc);
            acc = fmaf(qsm[wave][d + 1], kv.y, acc);
            acc = fmaf(qsm[wave][d + 2], kv.z, acc);
            acc = fmaf(qsm[wave][d + 3], kv.w, acc);
        }
        sc = acc + rpb[h * 169 + (pi + ki) * 13 + (pj + kj)];
    }
    float m = sc;
    #pragma unroll
    for (int off = 32; off > 0; off >>= 1) m = fmaxf(m, __shfl_xor(m, off));
    float e = (lane < KSZ * KSZ) ? __expf(sc - m) : 0.f;
    float s = e;
    #pragma unroll
    for (int off = 32; off > 0; off >>= 1) s += __shfl_xor(s, off);
    aw[wave][lane] = e / s;
    rsm[wave][lane] = nrow;
    __syncthreads();

    if (lane < HD) {
        float acc = 0.f;
        for (int l = 0; l < KSZ * KSZ; ++l) {
            const float a = aw[wave][l];
            const size_t r = rowbase + rsm[wave][l];
            acc = fmaf(a, qkv[r * C3 + 512 + h * HD + lane], acc);
        }
        attn[(rowbase + pix) * DIMC + h * HD + lane] = acc;
    }
}

// ---------------- MFMA flash self-attention (v3).
// Block: 4 waves, one (b,h), 64 queries, 576 keys (one split).
// Wave: 16 queries. Swapped QK^T: S^T[key][q] = mfma(K_frag, Q_frag).
// PV: O^T[d][q] = mfma(Vt_frag, P_frag). Double-buffered LDS tiles.
__global__ __launch_bounds__(256)
void self_attn_flash(const float* __restrict__ qkv,
                     uint16_t* __restrict__ po, float2* __restrict__ pml)
{
    const int tid = threadIdx.x;
    const int lane = tid & 63, wv = tid >> 6;
    const int c = lane & 15, g = lane >> 4;   // MFMA col / k-group
    const int bid = blockIdx.x;               // [bh][qblk][split]
    const int split = bid & (KSPLIT - 1);
    const int qblk = (bid >> 2) % NQBLK;
    const int bh = bid / (KSPLIT * NQBLK);
    const int h = bh & (HEADS - 1);
    const int b = bh >> 3;
    const size_t rowbase = (size_t)b * NPIX;
    const int q = qblk * QB + wv * 16 + c;    // this lane's query column
    const float scale = 0.17677669529663687f;

    __shared__ __align__(16) uint16_t Ks[2][TK * ROWE];  // [key][d], 80B rows
    __shared__ __align__(16) uint16_t Vt[2][TK * ROWE];  // [d][key], 80B rows

    // Q fragment (B operand): B[k=d][n=q] = Q[q][d], lane holds d = g*8 + j
    frag8 qf;
    {
        const float* qp = qkv + (rowbase + q) * C3 + 768 + h * HD + g * 8;
        const float4 q0 = *reinterpret_cast<const float4*>(qp);
        const float4 q1 = *reinterpret_cast<const float4*>(qp + 4);
        qf.u[0] = cvtpk(q0.x * scale, q0.y * scale);
        qf.u[1] = cvtpk(q0.z * scale, q0.w * scale);
        qf.u[2] = cvtpk(q1.x * scale, q1.y * scale);
        qf.u[3] = cvtpk(q1.z * scale, q1.w * scale);
    }

    float m = -1e30f, l = 0.f;
    f32x4 of0 = {0.f, 0.f, 0.f, 0.f}, of1 = {0.f, 0.f, 0.f, 0.f};

    const int skey = tid >> 3, sdc = tid & 7;  // staging: key row, d-chunk

    // prologue: stage tile 0 into buffer 0
    {
        const float* kp = qkv + (rowbase + split * KCHUNK + skey) * C3 + 1024 + h * HD + sdc * 4;
        const float4 kv = *reinterpret_cast<const float4*>(kp);
        const float4 vv = *reinterpret_cast<const float4*>(kp + 256);
        uint2 kw;
        kw.x = cvtpk(kv.x, kv.y);
        kw.y = cvtpk(kv.z, kv.w);
        *reinterpret_cast<uint2*>(&Ks[0][skey * ROWE + sdc * 4]) = kw;
        Vt[0][(sdc * 4 + 0) * ROWE + skey] = f2bf(vv.x);
        Vt[0][(sdc * 4 + 1) * ROWE + skey] = f2bf(vv.y);
        Vt[0][(sdc * 4 + 2) * ROWE + skey] = f2bf(vv.z);
        Vt[0][(sdc * 4 + 3) * ROWE + skey] = f2bf(vv.w);
    }

    for (int t = 0; t < NTILES; ++t) {
        __syncthreads();   // staged writes for tile t visible; prev reads done

        // T14: issue next tile's global loads before compute, LDS-write after
        float4 nk, nv;
        const bool more = (t + 1 < NTILES);
        if (more) {
            const float* kp = qkv + (rowbase + split * KCHUNK + (t + 1) * TK + skey) * C3
                              + 1024 + h * HD + sdc * 4;
            nk = *reinterpret_cast<const float4*>(kp);
            nv = *reinterpret_cast<const float4*>(kp + 256);
        }

        const int cur = t & 1;
        // ---- QK^T (swapped): S^T frag mf rows = keys 16*mf + 4g + r, col q
        frag8 ka0, ka1;
        ka0.s = *reinterpret_cast<const short8*>(&Ks[cur][c * ROWE + g * 8]);
        ka1.s = *reinterpret_cast<const short8*>(&Ks[cur][(16 + c) * ROWE + g * 8]);
        f32x4 s0 = {0.f, 0.f, 0.f, 0.f}, s1 = {0.f, 0.f, 0.f, 0.f};
        s0 = __builtin_amdgcn_mfma_f32_16x16x32_bf16(ka0.s, qf.s, s0, 0, 0, 0);
        s1 = __builtin_amdgcn_mfma_f32_16x16x32_bf16(ka1.s, qf.s, s1, 0, 0, 0);

        // ---- online softmax over this tile's 32 keys (8 per lane, per query col)
        float p[8] = {s0[0], s0[1], s0[2], s0[3], s1[0], s1[1], s1[2], s1[3]};
        float tmax = fmaxf(fmaxf(fmaxf(p[0], p[1]), fmaxf(p[2], p[3])),
                           fmaxf(fmaxf(p[4], p[5]), fmaxf(p[6], p[7])));
        tmax = fmaxf(tmax, __shfl_xor(tmax, 16));
        tmax = fmaxf(tmax, __shfl_xor(tmax, 32));
        const float newm = fmaxf(m, tmax);
        const float corr = __expf(m - newm);
        m = newm;
        float sum = 0.f;
        #pragma unroll
        for (int j = 0; j < 8; ++j) { p[j] = __expf(p[j] - m); sum += p[j]; }
        sum += __shfl_xor(sum, 16);
        sum += __shfl_xor(sum, 32);
        l = l * corr + sum;
        of0 *= corr;
        of1 *= corr;

        // ---- pack P to bf16 pairs; source lane (g_s,c) holds keys 16f+4g_s+2u{,+1}
        uint32_t pk0[2], pk1[2];
        pk0[0] = cvtpk(p[0], p[1]); pk0[1] = cvtpk(p[2], p[3]);
        pk1[0] = cvtpk(p[4], p[5]); pk1[1] = cvtpk(p[6], p[7]);

        // ---- B operand for PV: reg t = keys 8g+2t{,+1}, col q
        // src lane = (2*(g&1) + (t>>1))*16 + c ; frag select by g>>1
        frag8 pb;
        const int sbase = (g & 1) * 32 + c;
        #pragma unroll
        for (int tt = 0; tt < 4; ++tt) {
            const int srcLane = sbase + ((tt >> 1) << 4);
            const uint32_t v0 = __shfl(pk0[tt & 1], srcLane);
            const uint32_t v1 = __shfl(pk1[tt & 1], srcLane);
            pb.u[tt] = (g >= 2) ? v1 : v0;
        }

        // ---- PV: O^T frag f rows = d 16f + 4g + r
        frag8 va0, va1;
        va0.s = *reinterpret_cast<const short8*>(&Vt[cur][c * ROWE + g * 8]);
        va1.s = *reinterpret_cast<const short8*>(&Vt[cur][(16 + c) * ROWE + g * 8]);
        of0 = __builtin_amdgcn_mfma_f32_16x16x32_bf16(va0.s, pb.s, of0, 0, 0, 0);
        of1 = __builtin_amdgcn_mfma_f32_16x16x32_bf16(va1.s, pb.s, of1, 0, 0, 0);

        // ---- write next tile to the other buffer
        if (more) {
            const int nxt = cur ^ 1;
            uint2 kw;
            kw.x = cvtpk(nk.x, nk.y);
            kw.y = cvtpk(nk.z, nk.w);
            *reinterpret_cast<uint2*>(&Ks[nxt][skey * ROWE + sdc * 4]) = kw;
            Vt[nxt][(sdc * 4 + 0) * ROWE + skey] = f2bf(nv.x);
            Vt[nxt][(sdc * 4 + 1) * ROWE + skey] = f2bf(nv.y);
            Vt[nxt][(sdc * 4 + 2) * ROWE + skey] = f2bf(nv.z);
            Vt[nxt][(sdc * 4 + 3) * ROWE + skey] = f2bf(nv.w);
        }
    }

    // ---- store normalized bf16 partial + (m,l); lane (g,c): of0 -> d=4g+r, of1 -> d=16+4g+r
    const float invl = 1.f / l;
    const size_t item = ((size_t)split * 16 + bh) * NPIX + q;
    uint32_t* dst = reinterpret_cast<uint32_t*>(po + item * HD);
    dst[2 * g + 0] = cvtpk(of0[0] * invl, of0[1] * invl);
    dst[2 * g + 1] = cvtpk(of0[2] * invl, of0[3] * invl);
    dst[8 + 2 * g + 0] = cvtpk(of1[0] * invl, of1[1] * invl);
    dst[8 + 2 * g + 1] = cvtpk(of1[2] * invl, of1[3] * invl);
    if (g == 0) pml[item] = make_float2(m, l);
}

// ---------------- Combine split-K partials -> attn[:, 256:512) (unchanged)
__global__ __launch_bounds__(256)
void self_attn_combine(const uint16_t* __restrict__ po, const float2* __restrict__ pml,
                       float* __restrict__ attn)
{
    const int idx = blockIdx.x * 256 + threadIdx.x;   // 16*2304*32
    const int d = idx & (HD - 1);
    const int q = (idx >> 5) % NPIX;
    const int bh = idx / (HD * NPIX);
    const int h = bh & (HEADS - 1);
    const int b = bh >> 3;

    float2 ml[KSPLIT];
    float M = -1e30f;
    #pragma unroll
    for (int s = 0; s < KSPLIT; ++s) {
        ml[s] = pml[((size_t)s * 16 + bh) * NPIX + q];
        M = fmaxf(M, ml[s].x);
    }
    float num = 0.f, den = 0.f;
    #pragma unroll
    for (int s = 0; s < KSPLIT; ++s) {
        const float w = __expf(ml[s].x - M) * ml[s].y;
        const float o = bf2f((uint32_t)po[(((size_t)s * 16 + bh) * NPIX + q) * HD + d]);
        num = fmaf(w, o, num);
        den += w;
    }
    attn[((size_t)b * NPIX + q) * DIMC + 256 + h * HD + d] = num / den;
}

extern "C" void kernel_launch(void* const* d_in, const int* in_sizes, int n_in,
                              void* d_out, int out_size, void* d_ws, size_t ws_size,
                              hipStream_t stream)
{
    const float* x     = (const float*)d_in[0];
    const float* Wqkv  = (const float*)d_in[1];
    const float* bqkv  = (const float*)d_in[2];
    const float* rpb   = (const float*)d_in[3];
    const float* Wproj = (const float*)d_in[4];
    const float* bproj = (const float*)d_in[5];

    float* qkv  = (float*)d_ws;                           // ROWS x C3 fp32   (28.3 MB)
    float* attn = qkv + (size_t)ROWS * C3;                // ROWS x DIMC fp32 ( 9.4 MB)
    float2* pml = (float2*)(attn + (size_t)ROWS * DIMC);  // KSPLIT*16*NPIX   ( 1.2 MB)
    uint16_t* po = (uint16_t*)d_out;                      // partial bf16 scratch, dead after combine

    const dim3 blk(256);
    gemm_bias<64, 64, 16><<<dim3(C3 / 64, ROWS / 64), blk, 0, stream>>>(
        x, Wqkv, bqkv, qkv, ROWS, C3, DIMC);
    na_attn<<<dim3((BB * HEADS * NPIX) / 4), blk, 0, stream>>>(qkv, rpb, attn);
    self_attn_flash<<<dim3(16 * NQBLK * KSPLIT), blk, 0, stream>>>(qkv, po, pml);
    self_attn_combine<<<dim3((16 * NPIX * HD) / 256), blk, 0, stream>>>(po, pml, attn);
    gemm_bias<64, 64, 16><<<dim3(DIMC / 64, ROWS / 64), blk, 0, stream>>>(
        attn, Wproj, bproj, (float*)d_out, ROWS, DIMC, DIMC);
}

// Round 9
// 157.062 us; speedup vs baseline: 5.3509x; 1.7193x over previous
//
#include <hip/hip_runtime.h>
#include <cstdint>
#include <cstddef>

// MixedAttention: cvt/transpose -> MFMA qkv GEMM -> {na attn | MFMA flash} -> MFMA proj GEMM
// Inputs fp32, output fp32. All intermediates bf16 (qkv, attn, xb, Wt).
// r9 fix: gemm_mfma staged only 64 of 128 tile rows -> uninit LDS -> NaN.

#define DIMC 512
#define HEADS 8
#define HD 32
#define KSZ 7
#define HH 48
#define WW 48
#define BB 2
#define NPIX (HH * WW)         // 2304
#define ROWS (BB * NPIX)       // 4608
#define C3 (3 * DIMC)          // 1536
#define TK 32                  // flash key tile
#define KSPLIT 4
#define KCHUNK (NPIX / KSPLIT) // 576
#define NTILES (KCHUNK / TK)   // 18
#define QB 64
#define NQBLK (NPIX / QB)      // 36
#define ROWE 40                // LDS row stride bf16 (80B: 16B-aligned, 2-way banks)

typedef __attribute__((ext_vector_type(8))) short short8;
typedef __attribute__((ext_vector_type(4))) float f32x4;
union frag8 { short8 s; uint32_t u[4]; };

static __device__ __forceinline__ float bf2f(uint32_t u) {
    return __builtin_bit_cast(float, u << 16);
}
static __device__ __forceinline__ uint16_t f2bf(float f) {
    uint32_t x = __builtin_bit_cast(uint32_t, f);
    uint32_t r = x + 0x7fffu + ((x >> 16) & 1u);
    return (uint16_t)(r >> 16);
}
static __device__ __forceinline__ uint32_t cvtpk(float lo, float hi) {
    uint32_t r;
    asm("v_cvt_pk_bf16_f32 %0, %1, %2" : "=v"(r) : "v"(lo), "v"(hi));
    return r;
}

// ---------------- fp32 -> bf16 elementwise (n multiple of 8)
__global__ __launch_bounds__(256)
void cvt_f32_bf16(const float* __restrict__ in, uint16_t* __restrict__ out, int n)
{
    const int i = (blockIdx.x * 256 + threadIdx.x) * 8;
    if (i >= n) return;
    const float4 v0 = *reinterpret_cast<const float4*>(in + i);
    const float4 v1 = *reinterpret_cast<const float4*>(in + i + 4);
    uint4 st;
    st.x = (uint32_t)f2bf(v0.x) | ((uint32_t)f2bf(v0.y) << 16);
    st.y = (uint32_t)f2bf(v0.z) | ((uint32_t)f2bf(v0.w) << 16);
    st.z = (uint32_t)f2bf(v1.x) | ((uint32_t)f2bf(v1.y) << 16);
    st.w = (uint32_t)f2bf(v1.z) | ((uint32_t)f2bf(v1.w) << 16);
    *reinterpret_cast<uint4*>(out + i) = st;
}

// ---------------- W[K][N] fp32 -> Wt[N][K] bf16 (K,N multiples of 32)
__global__ __launch_bounds__(256)
void transpose_to_bf16(const float* __restrict__ W, uint16_t* __restrict__ Wt,
                       int K, int N)
{
    __shared__ float tile[32][33];
    const int tx = threadIdx.x & 31, ty = threadIdx.x >> 5;   // ty in [0,8)
    const int k0 = blockIdx.x * 32, n0 = blockIdx.y * 32;
    #pragma unroll
    for (int i = 0; i < 4; ++i)
        tile[ty + 8 * i][tx] = W[(size_t)(k0 + ty + 8 * i) * N + n0 + tx];
    __syncthreads();
    #pragma unroll
    for (int i = 0; i < 4; ++i)
        Wt[(size_t)(n0 + ty + 8 * i) * K + k0 + tx] = f2bf(tile[tx][ty + 8 * i]);
}

// ---------------- MFMA GEMM: C[M,N] = A_bf16[M][K] * Bt_bf16[N][K]^T + bias
// 128x128 tile, BK=32, 4 waves (2x2), 4x4 16x16x32 frags per wave.
template<bool OUT_F32>
__global__ __launch_bounds__(256)
void gemm_mfma(const uint16_t* __restrict__ A, const uint16_t* __restrict__ Bt,
               const float* __restrict__ bias, void* __restrict__ Cv,
               int M, int N, int K)
{
    constexpr int BM = 128, BN = 128, BK = 32;
    __shared__ __align__(16) uint16_t Al[BM * ROWE];
    __shared__ __align__(16) uint16_t Bl[BN * ROWE];
    const int tid = threadIdx.x;
    const int lane = tid & 63, wv = tid >> 6;
    const int c = lane & 15, g = lane >> 4;
    const int wr = wv >> 1, wc = wv & 1;
    const int m0 = blockIdx.y * BM, n0 = blockIdx.x * BN;
    const int srow = tid >> 2, skc = (tid & 3) * 8;   // staging: row (x2), k-chunk

    f32x4 acc[4][4];
    #pragma unroll
    for (int mi = 0; mi < 4; ++mi)
        #pragma unroll
        for (int ni = 0; ni < 4; ++ni)
            acc[mi][ni] = (f32x4){0.f, 0.f, 0.f, 0.f};

    for (int k0 = 0; k0 < K; k0 += BK) {
        __syncthreads();
        // full 128x32 tiles: each thread stages rows srow and srow+64
        *reinterpret_cast<uint4*>(&Al[srow * ROWE + skc]) =
            *reinterpret_cast<const uint4*>(&A[(size_t)(m0 + srow) * K + k0 + skc]);
        *reinterpret_cast<uint4*>(&Al[(srow + 64) * ROWE + skc]) =
            *reinterpret_cast<const uint4*>(&A[(size_t)(m0 + srow + 64) * K + k0 + skc]);
        *reinterpret_cast<uint4*>(&Bl[srow * ROWE + skc]) =
            *reinterpret_cast<const uint4*>(&Bt[(size_t)(n0 + srow) * K + k0 + skc]);
        *reinterpret_cast<uint4*>(&Bl[(srow + 64) * ROWE + skc]) =
            *reinterpret_cast<const uint4*>(&Bt[(size_t)(n0 + srow + 64) * K + k0 + skc]);
        __syncthreads();

        frag8 a[4], b[4];
        #pragma unroll
        for (int mi = 0; mi < 4; ++mi)
            a[mi].s = *reinterpret_cast<const short8*>(&Al[(wr * 64 + mi * 16 + c) * ROWE + g * 8]);
        #pragma unroll
        for (int ni = 0; ni < 4; ++ni)
            b[ni].s = *reinterpret_cast<const short8*>(&Bl[(wc * 64 + ni * 16 + c) * ROWE + g * 8]);
        #pragma unroll
        for (int mi = 0; mi < 4; ++mi)
            #pragma unroll
            for (int ni = 0; ni < 4; ++ni)
                acc[mi][ni] = __builtin_amdgcn_mfma_f32_16x16x32_bf16(
                    a[mi].s, b[ni].s, acc[mi][ni], 0, 0, 0);
    }

    #pragma unroll
    for (int mi = 0; mi < 4; ++mi) {
        #pragma unroll
        for (int ni = 0; ni < 4; ++ni) {
            const int row = m0 + wr * 64 + mi * 16 + 4 * g;
            const int col = n0 + wc * 64 + ni * 16 + c;
            const float bv = bias[col];
            #pragma unroll
            for (int r = 0; r < 4; ++r) {
                const float val = acc[mi][ni][r] + bv;
                if (OUT_F32)
                    ((float*)Cv)[(size_t)(row + r) * N + col] = val;
                else
                    ((uint16_t*)Cv)[(size_t)(row + r) * N + col] = f2bf(val);
            }
        }
    }
}

// ---------------- Neighborhood attention (bf16 qkv/attn)
__global__ __launch_bounds__(256)
void na_attn(const uint16_t* __restrict__ qkv, const float* __restrict__ rpb,
             uint16_t* __restrict__ attn)
{
    const int wave = threadIdx.x >> 6, lane = threadIdx.x & 63;
    const int item = blockIdx.x * 4 + wave;
    const int pix = item % NPIX;
    const int bh = item / NPIX;
    const int h = bh & (HEADS - 1);
    const int b = bh >> 3;
    const int i = pix / WW, j = pix % WW;
    const int ni = min(max(i - 3, 0), HH - KSZ);
    const int nj = min(max(j - 3, 0), WW - KSZ);
    const int pi = 3 + max(3 - i, 0) + ((i + 3 >= HH) ? (HH - i - 4) : 0);
    const int pj = 3 + max(3 - j, 0) + ((j + 3 >= WW) ? (WW - j - 4) : 0);
    const float scale = 0.17677669529663687f;

    __shared__ float qsm[4][HD];
    __shared__ float aw[4][64];
    __shared__ int   rsm[4][64];

    const size_t rowbase = (size_t)b * NPIX;
    if (lane < HD)
        qsm[wave][lane] = bf2f((uint32_t)qkv[(rowbase + pix) * C3 + h * HD + lane]) * scale;
    __syncthreads();

    float sc = -1e30f;
    int nrow = 0;
    if (lane < KSZ * KSZ) {
        const int ki = lane / KSZ, kj = lane % KSZ;
        nrow = (ni + ki) * WW + (nj + kj);
        const uint16_t* kp = qkv + (rowbase + nrow) * C3 + 256 + h * HD;
        float acc = 0.f;
        #pragma unroll
        for (int d = 0; d < HD; d += 4) {
            const uint2 raw = *reinterpret_cast<const uint2*>(kp + d);
            acc = fmaf(qsm[wave][d + 0], bf2f(raw.x & 0xffffu), acc);
            acc = fmaf(qsm[wave][d + 1], bf2f(raw.x >> 16), acc);
            acc = fmaf(qsm[wave][d + 2], bf2f(raw.y & 0xffffu), acc);
            acc = fmaf(qsm[wave][d + 3], bf2f(raw.y >> 16), acc);
        }
        sc = acc + rpb[h * 169 + (pi + ki) * 13 + (pj + kj)];
    }
    float m = sc;
    #pragma unroll
    for (int off = 32; off > 0; off >>= 1) m = fmaxf(m, __shfl_xor(m, off));
    float e = (lane < KSZ * KSZ) ? __expf(sc - m) : 0.f;
    float s = e;
    #pragma unroll
    for (int off = 32; off > 0; off >>= 1) s += __shfl_xor(s, off);
    aw[wave][lane] = e / s;
    rsm[wave][lane] = nrow;
    __syncthreads();

    if (lane < HD) {
        float acc = 0.f;
        for (int l = 0; l < KSZ * KSZ; ++l) {
            const float a = aw[wave][l];
            const size_t r = rowbase + rsm[wave][l];
            acc = fmaf(a, bf2f((uint32_t)qkv[r * C3 + 512 + h * HD + lane]), acc);
        }
        attn[(rowbase + pix) * DIMC + h * HD + lane] = f2bf(acc);
    }
}

// ---------------- MFMA flash self-attention (bf16 qkv). Structure = round-7 v3.
__global__ __launch_bounds__(256)
void self_attn_flash(const uint16_t* __restrict__ qkv,
                     uint16_t* __restrict__ po, float2* __restrict__ pml)
{
    const int tid = threadIdx.x;
    const int lane = tid & 63, wv = tid >> 6;
    const int c = lane & 15, g = lane >> 4;
    const int bid = blockIdx.x;               // [bh][qblk][split]
    const int split = bid & (KSPLIT - 1);
    const int qblk = (bid >> 2) % NQBLK;
    const int bh = bid / (KSPLIT * NQBLK);
    const int h = bh & (HEADS - 1);
    const int b = bh >> 3;
    const size_t rowbase = (size_t)b * NPIX;
    const int q = qblk * QB + wv * 16 + c;
    const float scale = 0.17677669529663687f;

    __shared__ __align__(16) uint16_t Ks[2][TK * ROWE];
    __shared__ __align__(16) uint16_t Vt[2][TK * ROWE];

    // Q fragment (B operand), raw bf16; scale folded into post-MFMA scores
    frag8 qf;
    qf.s = *reinterpret_cast<const short8*>(qkv + (rowbase + q) * C3 + 768 + h * HD + g * 8);

    float m = -1e30f, l = 0.f;
    f32x4 of0 = {0.f, 0.f, 0.f, 0.f}, of1 = {0.f, 0.f, 0.f, 0.f};

    const int skey = tid >> 3, sdc = tid & 7;

    {   // prologue: stage tile 0
        const uint16_t* kp = qkv + (rowbase + split * KCHUNK + skey) * C3 + 1024 + h * HD + sdc * 4;
        const uint2 kw = *reinterpret_cast<const uint2*>(kp);
        const uint2 vw = *reinterpret_cast<const uint2*>(kp + 256);
        *reinterpret_cast<uint2*>(&Ks[0][skey * ROWE + sdc * 4]) = kw;
        Vt[0][(sdc * 4 + 0) * ROWE + skey] = (uint16_t)(vw.x & 0xffffu);
        Vt[0][(sdc * 4 + 1) * ROWE + skey] = (uint16_t)(vw.x >> 16);
        Vt[0][(sdc * 4 + 2) * ROWE + skey] = (uint16_t)(vw.y & 0xffffu);
        Vt[0][(sdc * 4 + 3) * ROWE + skey] = (uint16_t)(vw.y >> 16);
    }

    for (int t = 0; t < NTILES; ++t) {
        __syncthreads();

        uint2 nk, nv;
        const bool more = (t + 1 < NTILES);
        if (more) {   // T14: issue early
            const uint16_t* kp = qkv + (rowbase + split * KCHUNK + (t + 1) * TK + skey) * C3
                                 + 1024 + h * HD + sdc * 4;
            nk = *reinterpret_cast<const uint2*>(kp);
            nv = *reinterpret_cast<const uint2*>(kp + 256);
        }

        const int cur = t & 1;
        frag8 ka0, ka1;
        ka0.s = *reinterpret_cast<const short8*>(&Ks[cur][c * ROWE + g * 8]);
        ka1.s = *reinterpret_cast<const short8*>(&Ks[cur][(16 + c) * ROWE + g * 8]);
        f32x4 s0 = {0.f, 0.f, 0.f, 0.f}, s1 = {0.f, 0.f, 0.f, 0.f};
        s0 = __builtin_amdgcn_mfma_f32_16x16x32_bf16(ka0.s, qf.s, s0, 0, 0, 0);
        s1 = __builtin_amdgcn_mfma_f32_16x16x32_bf16(ka1.s, qf.s, s1, 0, 0, 0);

        float p[8] = {s0[0] * scale, s0[1] * scale, s0[2] * scale, s0[3] * scale,
                      s1[0] * scale, s1[1] * scale, s1[2] * scale, s1[3] * scale};
        float tmax = fmaxf(fmaxf(fmaxf(p[0], p[1]), fmaxf(p[2], p[3])),
                           fmaxf(fmaxf(p[4], p[5]), fmaxf(p[6], p[7])));
        tmax = fmaxf(tmax, __shfl_xor(tmax, 16));
        tmax = fmaxf(tmax, __shfl_xor(tmax, 32));
        const float newm = fmaxf(m, tmax);
        const float corr = __expf(m - newm);
        m = newm;
        float sum = 0.f;
        #pragma unroll
        for (int j = 0; j < 8; ++j) { p[j] = __expf(p[j] - m); sum += p[j]; }
        sum += __shfl_xor(sum, 16);
        sum += __shfl_xor(sum, 32);
        l = l * corr + sum;
        of0 *= corr;
        of1 *= corr;

        uint32_t pk0[2], pk1[2];
        pk0[0] = cvtpk(p[0], p[1]); pk0[1] = cvtpk(p[2], p[3]);
        pk1[0] = cvtpk(p[4], p[5]); pk1[1] = cvtpk(p[6], p[7]);

        frag8 pb;
        const int sbase = (g & 1) * 32 + c;
        #pragma unroll
        for (int tt = 0; tt < 4; ++tt) {
            const int srcLane = sbase + ((tt >> 1) << 4);
            const uint32_t v0 = __shfl(pk0[tt & 1], srcLane);
            const uint32_t v1 = __shfl(pk1[tt & 1], srcLane);
            pb.u[tt] = (g >= 2) ? v1 : v0;
        }

        frag8 va0, va1;
        va0.s = *reinterpret_cast<const short8*>(&Vt[cur][c * ROWE + g * 8]);
        va1.s = *reinterpret_cast<const short8*>(&Vt[cur][(16 + c) * ROWE + g * 8]);
        of0 = __builtin_amdgcn_mfma_f32_16x16x32_bf16(va0.s, pb.s, of0, 0, 0, 0);
        of1 = __builtin_amdgcn_mfma_f32_16x16x32_bf16(va1.s, pb.s, of1, 0, 0, 0);

        if (more) {   // write late
            const int nxt = cur ^ 1;
            *reinterpret_cast<uint2*>(&Ks[nxt][skey * ROWE + sdc * 4]) = nk;
            Vt[nxt][(sdc * 4 + 0) * ROWE + skey] = (uint16_t)(nv.x & 0xffffu);
            Vt[nxt][(sdc * 4 + 1) * ROWE + skey] = (uint16_t)(nv.x >> 16);
            Vt[nxt][(sdc * 4 + 2) * ROWE + skey] = (uint16_t)(nv.y & 0xffffu);
            Vt[nxt][(sdc * 4 + 3) * ROWE + skey] = (uint16_t)(nv.y >> 16);
        }
    }

    const float invl = 1.f / l;
    const size_t item = ((size_t)split * 16 + bh) * NPIX + q;
    uint32_t* dst = reinterpret_cast<uint32_t*>(po + item * HD);
    dst[2 * g + 0] = cvtpk(of0[0] * invl, of0[1] * invl);
    dst[2 * g + 1] = cvtpk(of0[2] * invl, of0[3] * invl);
    dst[8 + 2 * g + 0] = cvtpk(of1[0] * invl, of1[1] * invl);
    dst[8 + 2 * g + 1] = cvtpk(of1[2] * invl, of1[3] * invl);
    if (g == 0) pml[item] = make_float2(m, l);
}

// ---------------- Combine split-K partials -> attn[:, 256:512) bf16
__global__ __launch_bounds__(256)
void self_attn_combine(const uint16_t* __restrict__ po, const float2* __restrict__ pml,
                       uint16_t* __restrict__ attn)
{
    const int idx = blockIdx.x * 256 + threadIdx.x;
    const int d = idx & (HD - 1);
    const int q = (idx >> 5) % NPIX;
    const int bh = idx / (HD * NPIX);
    const int h = bh & (HEADS - 1);
    const int b = bh >> 3;

    float2 ml[KSPLIT];
    float M = -1e30f;
    #pragma unroll
    for (int s = 0; s < KSPLIT; ++s) {
        ml[s] = pml[((size_t)s * 16 + bh) * NPIX + q];
        M = fmaxf(M, ml[s].x);
    }
    float num = 0.f, den = 0.f;
    #pragma unroll
    for (int s = 0; s < KSPLIT; ++s) {
        const float w = __expf(ml[s].x - M) * ml[s].y;
        const float o = bf2f((uint32_t)po[(((size_t)s * 16 + bh) * NPIX + q) * HD + d]);
        num = fmaf(w, o, num);
        den += w;
    }
    attn[((size_t)b * NPIX + q) * DIMC + 256 + h * HD + d] = f2bf(num / den);
}

extern "C" void kernel_launch(void* const* d_in, const int* in_sizes, int n_in,
                              void* d_out, int out_size, void* d_ws, size_t ws_size,
                              hipStream_t stream)
{
    const float* x     = (const float*)d_in[0];
    const float* Wqkv  = (const float*)d_in[1];
    const float* bqkv  = (const float*)d_in[2];
    const float* rpb   = (const float*)d_in[3];
    const float* Wproj = (const float*)d_in[4];
    const float* bproj = (const float*)d_in[5];

    uint16_t* qkv  = (uint16_t*)d_ws;                     // [ROWS][C3]   14.2 MB
    uint16_t* attn = qkv + (size_t)ROWS * C3;             // [ROWS][DIMC]  4.7 MB
    uint16_t* xb   = attn + (size_t)ROWS * DIMC;          // [ROWS][DIMC]  4.7 MB
    uint16_t* wqt  = xb + (size_t)ROWS * DIMC;            // [C3][DIMC]    1.6 MB
    uint16_t* wpt  = wqt + (size_t)C3 * DIMC;             // [DIMC][DIMC]  0.5 MB
    float2*   pml  = (float2*)(wpt + (size_t)DIMC * DIMC);// 4*16*NPIX     1.2 MB
    uint16_t* po   = (uint16_t*)d_out;                    // partial scratch (dead until gemm2)

    const dim3 blk(256);
    // prep: x -> bf16; W -> bf16 transposed [N][K]
    cvt_f32_bf16<<<dim3((ROWS * DIMC) / (256 * 8)), blk, 0, stream>>>(x, xb, ROWS * DIMC);
    transpose_to_bf16<<<dim3(DIMC / 32, C3 / 32), blk, 0, stream>>>(Wqkv, wqt, DIMC, C3);
    transpose_to_bf16<<<dim3(DIMC / 32, DIMC / 32), blk, 0, stream>>>(Wproj, wpt, DIMC, DIMC);
    // qkv = x @ W_qkv + b  (bf16 out)
    gemm_mfma<false><<<dim3(C3 / 128, ROWS / 128), blk, 0, stream>>>(
        xb, wqt, bqkv, qkv, ROWS, C3, DIMC);
    // attention halves
    na_attn<<<dim3((BB * HEADS * NPIX) / 4), blk, 0, stream>>>(qkv, rpb, attn);
    self_attn_flash<<<dim3(16 * NQBLK * KSPLIT), blk, 0, stream>>>(qkv, po, pml);
    self_attn_combine<<<dim3((16 * NPIX * HD) / 256), blk, 0, stream>>>(po, pml, attn);
    // out = attn @ W_proj + b  (fp32 out)
    gemm_mfma<true><<<dim3(DIMC / 128, ROWS / 128), blk, 0, stream>>>(
        attn, wpt, bproj, d_out, ROWS, DIMC, DIMC);
}

// Round 10
// 114.702 us; speedup vs baseline: 7.3270x; 1.3693x over previous
//
#include <hip/hip_runtime.h>
#include <cstdint>
#include <cstddef>

// MixedAttention: transpose-W -> MFMA qkv GEMM (fused f32->bf16) ->
// {tile-MFMA na attn | MFMA flash self attn} -> MFMA proj GEMM
// Inputs fp32, output fp32. Intermediates bf16.

#define DIMC 512
#define HEADS 8
#define HD 32
#define KSZ 7
#define HH 48
#define WW 48
#define BB 2
#define NPIX (HH * WW)         // 2304
#define ROWS (BB * NPIX)       // 4608
#define C3 (3 * DIMC)          // 1536
#define TK 32                  // flash key tile
#define KSPLIT 4
#define KCHUNK (NPIX / KSPLIT) // 576
#define NTILES (KCHUNK / TK)   // 18
#define QB 64
#define NQBLK (NPIX / QB)      // 36
#define ROWE 40                // LDS row stride bf16 (80B: 16B-aligned, 2-way banks)
#define VROWE 232              // na Vt row stride (464B: same bank residue class)

typedef __attribute__((ext_vector_type(8))) short short8;
typedef __attribute__((ext_vector_type(4))) float f32x4;
union frag8 { short8 s; uint32_t u[4]; };

static __device__ __forceinline__ float bf2f(uint32_t u) {
    return __builtin_bit_cast(float, u << 16);
}
static __device__ __forceinline__ uint16_t f2bf(float f) {
    uint32_t x = __builtin_bit_cast(uint32_t, f);
    uint32_t r = x + 0x7fffu + ((x >> 16) & 1u);
    return (uint16_t)(r >> 16);
}
static __device__ __forceinline__ uint32_t cvtpk(float lo, float hi) {
    uint32_t r;
    asm("v_cvt_pk_bf16_f32 %0, %1, %2" : "=v"(r) : "v"(lo), "v"(hi));
    return r;
}

// ---------------- W[K][N] fp32 -> Wt[N][K] bf16 (K,N multiples of 32)
__global__ __launch_bounds__(256)
void transpose_to_bf16(const float* __restrict__ W, uint16_t* __restrict__ Wt,
                       int K, int N)
{
    __shared__ float tile[32][33];
    const int tx = threadIdx.x & 31, ty = threadIdx.x >> 5;
    const int k0 = blockIdx.x * 32, n0 = blockIdx.y * 32;
    #pragma unroll
    for (int i = 0; i < 4; ++i)
        tile[ty + 8 * i][tx] = W[(size_t)(k0 + ty + 8 * i) * N + n0 + tx];
    __syncthreads();
    #pragma unroll
    for (int i = 0; i < 4; ++i)
        Wt[(size_t)(n0 + ty + 8 * i) * K + k0 + tx] = f2bf(tile[tx][ty + 8 * i]);
}

// ---------------- MFMA GEMM: C[M,N] = A[M][K] * Bt_bf16[N][K]^T + bias
// A fp32 (converted during staging) or bf16. 128x128 tile, BK=32, 4 waves.
template<bool A_F32, bool OUT_F32>
__global__ __launch_bounds__(256)
void gemm_mfma(const void* __restrict__ Av, const uint16_t* __restrict__ Bt,
               const float* __restrict__ bias, void* __restrict__ Cv,
               int M, int N, int K)
{
    constexpr int BM = 128, BK = 32;
    __shared__ __align__(16) uint16_t Al[BM * ROWE];
    __shared__ __align__(16) uint16_t Bl[BM * ROWE];
    const int tid = threadIdx.x;
    const int lane = tid & 63, wv = tid >> 6;
    const int c = lane & 15, g = lane >> 4;
    const int wr = wv >> 1, wc = wv & 1;
    const int m0 = blockIdx.y * BM, n0 = blockIdx.x * BM;
    const int srow = tid >> 2, skc = (tid & 3) * 8;

    f32x4 acc[4][4];
    #pragma unroll
    for (int mi = 0; mi < 4; ++mi)
        #pragma unroll
        for (int ni = 0; ni < 4; ++ni)
            acc[mi][ni] = (f32x4){0.f, 0.f, 0.f, 0.f};

    for (int k0 = 0; k0 < K; k0 += BK) {
        __syncthreads();
        #pragma unroll
        for (int half = 0; half < 2; ++half) {
            const int row = srow + half * 64;
            if (A_F32) {
                const float* A32 = (const float*)Av;
                const float4 a0 = *reinterpret_cast<const float4*>(&A32[(size_t)(m0 + row) * K + k0 + skc]);
                const float4 a1 = *reinterpret_cast<const float4*>(&A32[(size_t)(m0 + row) * K + k0 + skc + 4]);
                *reinterpret_cast<uint4*>(&Al[row * ROWE + skc]) =
                    make_uint4(cvtpk(a0.x, a0.y), cvtpk(a0.z, a0.w),
                               cvtpk(a1.x, a1.y), cvtpk(a1.z, a1.w));
            } else {
                const uint16_t* A16 = (const uint16_t*)Av;
                *reinterpret_cast<uint4*>(&Al[row * ROWE + skc]) =
                    *reinterpret_cast<const uint4*>(&A16[(size_t)(m0 + row) * K + k0 + skc]);
            }
            *reinterpret_cast<uint4*>(&Bl[row * ROWE + skc]) =
                *reinterpret_cast<const uint4*>(&Bt[(size_t)(n0 + row) * K + k0 + skc]);
        }
        __syncthreads();

        frag8 a[4], b[4];
        #pragma unroll
        for (int mi = 0; mi < 4; ++mi)
            a[mi].s = *reinterpret_cast<const short8*>(&Al[(wr * 64 + mi * 16 + c) * ROWE + g * 8]);
        #pragma unroll
        for (int ni = 0; ni < 4; ++ni)
            b[ni].s = *reinterpret_cast<const short8*>(&Bl[(wc * 64 + ni * 16 + c) * ROWE + g * 8]);
        #pragma unroll
        for (int mi = 0; mi < 4; ++mi)
            #pragma unroll
            for (int ni = 0; ni < 4; ++ni)
                acc[mi][ni] = __builtin_amdgcn_mfma_f32_16x16x32_bf16(
                    a[mi].s, b[ni].s, acc[mi][ni], 0, 0, 0);
    }

    #pragma unroll
    for (int mi = 0; mi < 4; ++mi) {
        #pragma unroll
        for (int ni = 0; ni < 4; ++ni) {
            const int row = m0 + wr * 64 + mi * 16 + 4 * g;
            const int col = n0 + wc * 64 + ni * 16 + c;
            const float bv = bias[col];
            #pragma unroll
            for (int r = 0; r < 4; ++r) {
                const float val = acc[mi][ni][r] + bv;
                if (OUT_F32)
                    ((float*)Cv)[(size_t)(row + r) * N + col] = val;
                else
                    ((uint16_t*)Cv)[(size_t)(row + r) * N + col] = f2bf(val);
            }
        }
    }
}

// ---------------- Tile-MFMA neighborhood attention.
// Block: one (b,h) + 8x8 pixel tile; 4 waves x 16 queries. Key union 14x14
// padded to 224 = 14x16 so key u = 16f + (4g+r): ur=f (static), uc=4g+r.
// Swapped QK^T + single-pass softmax + flash-style P repack + Vt PV.
__global__ __launch_bounds__(256)
void na_attn_mfma(const uint16_t* __restrict__ qkv, const float* __restrict__ rpb,
                  uint16_t* __restrict__ attn)
{
    const int tid = threadIdx.x;
    const int lane = tid & 63, wv = tid >> 6;
    const int c = lane & 15, g = lane >> 4, g4 = g * 4;
    const int bid = blockIdx.x;
    const int tile = bid % 36;
    const int bh = bid / 36;
    const int h = bh & (HEADS - 1), b = bh >> 3;
    const int t0i = (tile / 6) * 8, t0j = (tile % 6) * 8;
    const int u0i = min(max(t0i - 3, 0), HH - 14);
    const int u0j = min(max(t0j - 3, 0), WW - 14);
    const size_t rowbase = (size_t)b * NPIX;
    const float scale = 0.17677669529663687f;

    __shared__ __align__(16) uint16_t K_l[224 * ROWE];
    __shared__ __align__(16) uint16_t Vt[32 * VROWE];
    __shared__ float rpb_l[169];

    if (tid < 169) rpb_l[tid] = rpb[h * 169 + tid];
    #pragma unroll
    for (int it = 0; it < 4; ++it) {
        const int idx = it * 256 + tid;
        if (idx < 896) {
            const int u = idx >> 2, dc = idx & 3;
            const int uc = u & 15, ur = u >> 4;
            if (uc < 14) {
                const int grow = (u0i + ur) * WW + (u0j + uc);
                const uint16_t* src = qkv + (rowbase + grow) * C3 + 256 + h * HD + dc * 8;
                *reinterpret_cast<uint4*>(&K_l[u * ROWE + dc * 8]) =
                    *reinterpret_cast<const uint4*>(src);
                const uint4 vw = *reinterpret_cast<const uint4*>(src + 256);  // V at +512
                const uint16_t* vh = reinterpret_cast<const uint16_t*>(&vw);
                #pragma unroll
                for (int i = 0; i < 8; ++i)
                    Vt[(dc * 8 + i) * VROWE + u] = vh[i];
            } else {
                *reinterpret_cast<uint4*>(&K_l[u * ROWE + dc * 8]) = make_uint4(0, 0, 0, 0);
                #pragma unroll
                for (int i = 0; i < 8; ++i)
                    Vt[(dc * 8 + i) * VROWE + u] = 0;
            }
        }
    }

    // per-lane query geometry
    const int qid = wv * 16 + c;
    const int qi = t0i + (qid >> 3), qj = t0j + (qid & 7);
    const int pixq = qi * WW + qj;
    const int niq = min(max(qi - 3, 0), HH - KSZ);
    const int njq = min(max(qj - 3, 0), WW - KSZ);
    const int piq = 3 + max(3 - qi, 0) + ((qi + 3 >= HH) ? (HH - qi - 4) : 0);
    const int pjq = 3 + max(3 - qj, 0) + ((qj + 3 >= WW) ? (WW - qj - 4) : 0);
    const int ni_rel = niq - u0i, nj_rel = njq - u0j;
    const int bb = (piq - ni_rel) * 13 + (pjq - nj_rel);

    frag8 qf;
    qf.s = *reinterpret_cast<const short8*>(qkv + (rowbase + pixq) * C3 + h * HD + g * 8);

    __syncthreads();

    // QK^T over 14 key frags + mask + bias; scores stay in registers
    float pex[14][4];
    float m = -1e30f;
    #pragma unroll
    for (int f = 0; f < 14; ++f) {
        frag8 ka;
        ka.s = *reinterpret_cast<const short8*>(&K_l[(16 * f + c) * ROWE + g * 8]);
        f32x4 s = {0.f, 0.f, 0.f, 0.f};
        s = __builtin_amdgcn_mfma_f32_16x16x32_bf16(ka.s, qf.s, s, 0, 0, 0);
        const bool rok = (unsigned)(f - ni_rel) < 7u;
        #pragma unroll
        for (int r = 0; r < 4; ++r) {
            const int uc = g4 + r;
            const bool ok = rok && ((unsigned)(uc - nj_rel) < 7u);
            const int addr = ok ? (bb + 13 * f + uc) : 0;
            const float v = s[r] * scale + rpb_l[addr];
            pex[f][r] = ok ? v : -1e30f;
            m = fmaxf(m, pex[f][r]);
        }
    }
    m = fmaxf(m, __shfl_xor(m, 16));
    m = fmaxf(m, __shfl_xor(m, 32));
    float l = 0.f;
    #pragma unroll
    for (int f = 0; f < 14; ++f)
        #pragma unroll
        for (int r = 0; r < 4; ++r) {
            pex[f][r] = __expf(pex[f][r] - m);
            l += pex[f][r];
        }
    l += __shfl_xor(l, 16);
    l += __shfl_xor(l, 32);

    // PV over 7 chunks of 32 keys (flash-proven repack)
    f32x4 of0 = {0.f, 0.f, 0.f, 0.f}, of1 = {0.f, 0.f, 0.f, 0.f};
    const int sbase = (g & 1) * 32 + c;
    #pragma unroll
    for (int kk = 0; kk < 7; ++kk) {
        uint32_t pk0[2], pk1[2];
        pk0[0] = cvtpk(pex[2 * kk][0], pex[2 * kk][1]);
        pk0[1] = cvtpk(pex[2 * kk][2], pex[2 * kk][3]);
        pk1[0] = cvtpk(pex[2 * kk + 1][0], pex[2 * kk + 1][1]);
        pk1[1] = cvtpk(pex[2 * kk + 1][2], pex[2 * kk + 1][3]);
        frag8 pb;
        #pragma unroll
        for (int tt = 0; tt < 4; ++tt) {
            const int srcLane = sbase + ((tt >> 1) << 4);
            const uint32_t v0 = __shfl(pk0[tt & 1], srcLane);
            const uint32_t v1 = __shfl(pk1[tt & 1], srcLane);
            pb.u[tt] = (g >= 2) ? v1 : v0;
        }
        frag8 va0, va1;
        va0.s = *reinterpret_cast<const short8*>(&Vt[c * VROWE + kk * 32 + g * 8]);
        va1.s = *reinterpret_cast<const short8*>(&Vt[(16 + c) * VROWE + kk * 32 + g * 8]);
        of0 = __builtin_amdgcn_mfma_f32_16x16x32_bf16(va0.s, pb.s, of0, 0, 0, 0);
        of1 = __builtin_amdgcn_mfma_f32_16x16x32_bf16(va1.s, pb.s, of1, 0, 0, 0);
    }

    const float invl = 1.f / l;
    uint32_t* dst = reinterpret_cast<uint32_t*>(attn + (rowbase + pixq) * DIMC + h * HD);
    dst[2 * g + 0] = cvtpk(of0[0] * invl, of0[1] * invl);
    dst[2 * g + 1] = cvtpk(of0[2] * invl, of0[3] * invl);
    dst[8 + 2 * g + 0] = cvtpk(of1[0] * invl, of1[1] * invl);
    dst[8 + 2 * g + 1] = cvtpk(of1[2] * invl, of1[3] * invl);
}

// ---------------- MFMA flash self-attention (unchanged from round 9)
__global__ __launch_bounds__(256)
void self_attn_flash(const uint16_t* __restrict__ qkv,
                     uint16_t* __restrict__ po, float2* __restrict__ pml)
{
    const int tid = threadIdx.x;
    const int lane = tid & 63, wv = tid >> 6;
    const int c = lane & 15, g = lane >> 4;
    const int bid = blockIdx.x;
    const int split = bid & (KSPLIT - 1);
    const int qblk = (bid >> 2) % NQBLK;
    const int bh = bid / (KSPLIT * NQBLK);
    const int h = bh & (HEADS - 1);
    const int b = bh >> 3;
    const size_t rowbase = (size_t)b * NPIX;
    const int q = qblk * QB + wv * 16 + c;
    const float scale = 0.17677669529663687f;

    __shared__ __align__(16) uint16_t Ks[2][TK * ROWE];
    __shared__ __align__(16) uint16_t Vt[2][TK * ROWE];

    frag8 qf;
    qf.s = *reinterpret_cast<const short8*>(qkv + (rowbase + q) * C3 + 768 + h * HD + g * 8);

    float m = -1e30f, l = 0.f;
    f32x4 of0 = {0.f, 0.f, 0.f, 0.f}, of1 = {0.f, 0.f, 0.f, 0.f};

    const int skey = tid >> 3, sdc = tid & 7;

    {
        const uint16_t* kp = qkv + (rowbase + split * KCHUNK + skey) * C3 + 1024 + h * HD + sdc * 4;
        const uint2 kw = *reinterpret_cast<const uint2*>(kp);
        const uint2 vw = *reinterpret_cast<const uint2*>(kp + 256);
        *reinterpret_cast<uint2*>(&Ks[0][skey * ROWE + sdc * 4]) = kw;
        Vt[0][(sdc * 4 + 0) * ROWE + skey] = (uint16_t)(vw.x & 0xffffu);
        Vt[0][(sdc * 4 + 1) * ROWE + skey] = (uint16_t)(vw.x >> 16);
        Vt[0][(sdc * 4 + 2) * ROWE + skey] = (uint16_t)(vw.y & 0xffffu);
        Vt[0][(sdc * 4 + 3) * ROWE + skey] = (uint16_t)(vw.y >> 16);
    }

    for (int t = 0; t < NTILES; ++t) {
        __syncthreads();

        uint2 nk, nv;
        const bool more = (t + 1 < NTILES);
        if (more) {
            const uint16_t* kp = qkv + (rowbase + split * KCHUNK + (t + 1) * TK + skey) * C3
                                 + 1024 + h * HD + sdc * 4;
            nk = *reinterpret_cast<const uint2*>(kp);
            nv = *reinterpret_cast<const uint2*>(kp + 256);
        }

        const int cur = t & 1;
        frag8 ka0, ka1;
        ka0.s = *reinterpret_cast<const short8*>(&Ks[cur][c * ROWE + g * 8]);
        ka1.s = *reinterpret_cast<const short8*>(&Ks[cur][(16 + c) * ROWE + g * 8]);
        f32x4 s0 = {0.f, 0.f, 0.f, 0.f}, s1 = {0.f, 0.f, 0.f, 0.f};
        s0 = __builtin_amdgcn_mfma_f32_16x16x32_bf16(ka0.s, qf.s, s0, 0, 0, 0);
        s1 = __builtin_amdgcn_mfma_f32_16x16x32_bf16(ka1.s, qf.s, s1, 0, 0, 0);

        float p[8] = {s0[0] * scale, s0[1] * scale, s0[2] * scale, s0[3] * scale,
                      s1[0] * scale, s1[1] * scale, s1[2] * scale, s1[3] * scale};
        float tmax = fmaxf(fmaxf(fmaxf(p[0], p[1]), fmaxf(p[2], p[3])),
                           fmaxf(fmaxf(p[4], p[5]), fmaxf(p[6], p[7])));
        tmax = fmaxf(tmax, __shfl_xor(tmax, 16));
        tmax = fmaxf(tmax, __shfl_xor(tmax, 32));
        const float newm = fmaxf(m, tmax);
        const float corr = __expf(m - newm);
        m = newm;
        float sum = 0.f;
        #pragma unroll
        for (int j = 0; j < 8; ++j) { p[j] = __expf(p[j] - m); sum += p[j]; }
        sum += __shfl_xor(sum, 16);
        sum += __shfl_xor(sum, 32);
        l = l * corr + sum;
        of0 *= corr;
        of1 *= corr;

        uint32_t pk0[2], pk1[2];
        pk0[0] = cvtpk(p[0], p[1]); pk0[1] = cvtpk(p[2], p[3]);
        pk1[0] = cvtpk(p[4], p[5]); pk1[1] = cvtpk(p[6], p[7]);

        frag8 pb;
        const int sbase = (g & 1) * 32 + c;
        #pragma unroll
        for (int tt = 0; tt < 4; ++tt) {
            const int srcLane = sbase + ((tt >> 1) << 4);
            const uint32_t v0 = __shfl(pk0[tt & 1], srcLane);
            const uint32_t v1 = __shfl(pk1[tt & 1], srcLane);
            pb.u[tt] = (g >= 2) ? v1 : v0;
        }

        frag8 va0, va1;
        va0.s = *reinterpret_cast<const short8*>(&Vt[cur][c * ROWE + g * 8]);
        va1.s = *reinterpret_cast<const short8*>(&Vt[cur][(16 + c) * ROWE + g * 8]);
        of0 = __builtin_amdgcn_mfma_f32_16x16x32_bf16(va0.s, pb.s, of0, 0, 0, 0);
        of1 = __builtin_amdgcn_mfma_f32_16x16x32_bf16(va1.s, pb.s, of1, 0, 0, 0);

        if (more) {
            const int nxt = cur ^ 1;
            *reinterpret_cast<uint2*>(&Ks[nxt][skey * ROWE + sdc * 4]) = nk;
            Vt[nxt][(sdc * 4 + 0) * ROWE + skey] = (uint16_t)(nv.x & 0xffffu);
            Vt[nxt][(sdc * 4 + 1) * ROWE + skey] = (uint16_t)(nv.x >> 16);
            Vt[nxt][(sdc * 4 + 2) * ROWE + skey] = (uint16_t)(nv.y & 0xffffu);
            Vt[nxt][(sdc * 4 + 3) * ROWE + skey] = (uint16_t)(nv.y >> 16);
        }
    }

    const float invl = 1.f / l;
    const size_t item = ((size_t)split * 16 + bh) * NPIX + q;
    uint32_t* dst = reinterpret_cast<uint32_t*>(po + item * HD);
    dst[2 * g + 0] = cvtpk(of0[0] * invl, of0[1] * invl);
    dst[2 * g + 1] = cvtpk(of0[2] * invl, of0[3] * invl);
    dst[8 + 2 * g + 0] = cvtpk(of1[0] * invl, of1[1] * invl);
    dst[8 + 2 * g + 1] = cvtpk(of1[2] * invl, of1[3] * invl);
    if (g == 0) pml[item] = make_float2(m, l);
}

// ---------------- Combine split-K partials -> attn[:, 256:512) bf16
__global__ __launch_bounds__(256)
void self_attn_combine(const uint16_t* __restrict__ po, const float2* __restrict__ pml,
                       uint16_t* __restrict__ attn)
{
    const int idx = blockIdx.x * 256 + threadIdx.x;
    const int d = idx & (HD - 1);
    const int q = (idx >> 5) % NPIX;
    const int bh = idx / (HD * NPIX);
    const int h = bh & (HEADS - 1);
    const int b = bh >> 3;

    float2 ml[KSPLIT];
    float M = -1e30f;
    #pragma unroll
    for (int s = 0; s < KSPLIT; ++s) {
        ml[s] = pml[((size_t)s * 16 + bh) * NPIX + q];
        M = fmaxf(M, ml[s].x);
    }
    float num = 0.f, den = 0.f;
    #pragma unroll
    for (int s = 0; s < KSPLIT; ++s) {
        const float w = __expf(ml[s].x - M) * ml[s].y;
        const float o = bf2f((uint32_t)po[(((size_t)s * 16 + bh) * NPIX + q) * HD + d]);
        num = fmaf(w, o, num);
        den += w;
    }
    attn[((size_t)b * NPIX + q) * DIMC + 256 + h * HD + d] = f2bf(num / den);
}

extern "C" void kernel_launch(void* const* d_in, const int* in_sizes, int n_in,
                              void* d_out, int out_size, void* d_ws, size_t ws_size,
                              hipStream_t stream)
{
    const float* x     = (const float*)d_in[0];
    const float* Wqkv  = (const float*)d_in[1];
    const float* bqkv  = (const float*)d_in[2];
    const float* rpb   = (const float*)d_in[3];
    const float* Wproj = (const float*)d_in[4];
    const float* bproj = (const float*)d_in[5];

    uint16_t* qkv  = (uint16_t*)d_ws;                     // [ROWS][C3]   14.2 MB
    uint16_t* attn = qkv + (size_t)ROWS * C3;             // [ROWS][DIMC]  4.7 MB
    uint16_t* wqt  = attn + (size_t)ROWS * DIMC;          // [C3][DIMC]    1.6 MB
    uint16_t* wpt  = wqt + (size_t)C3 * DIMC;             // [DIMC][DIMC]  0.5 MB
    float2*   pml  = (float2*)(wpt + (size_t)DIMC * DIMC);// 4*16*NPIX     1.2 MB
    uint16_t* po   = (uint16_t*)d_out;                    // partial scratch (dead until gemm2)

    const dim3 blk(256);
    transpose_to_bf16<<<dim3(DIMC / 32, C3 / 32), blk, 0, stream>>>(Wqkv, wqt, DIMC, C3);
    transpose_to_bf16<<<dim3(DIMC / 32, DIMC / 32), blk, 0, stream>>>(Wproj, wpt, DIMC, DIMC);
    // qkv = x @ W_qkv + b  (fp32 A staged to bf16 in-kernel, bf16 out)
    gemm_mfma<true, false><<<dim3(C3 / 128, ROWS / 128), blk, 0, stream>>>(
        x, wqt, bqkv, qkv, ROWS, C3, DIMC);
    // attention halves
    na_attn_mfma<<<dim3(BB * HEADS * 36), blk, 0, stream>>>(qkv, rpb, attn);
    self_attn_flash<<<dim3(16 * NQBLK * KSPLIT), blk, 0, stream>>>(qkv, po, pml);
    self_attn_combine<<<dim3((16 * NPIX * HD) / 256), blk, 0, stream>>>(po, pml, attn);
    // out = attn @ W_proj + b  (bf16 A, fp32 out)
    gemm_mfma<false, true><<<dim3(DIMC / 128, ROWS / 128), blk, 0, stream>>>(
        attn, wpt, bproj, d_out, ROWS, DIMC, DIMC);
}

// Round 11
// 112.754 us; speedup vs baseline: 7.4536x; 1.0173x over previous
//
#include <hip/hip_runtime.h>
#include <cstdint>
#include <cstddef>

// MixedAttention: transpose-W -> MFMA qkv GEMM (fused f32->bf16) ->
// {tile-MFMA na attn | MFMA flash self attn} -> MFMA proj GEMM
// Inputs fp32, output fp32. Intermediates bf16.
// r11: flash = 32q/wave, Vt XOR-swizzle (kills 4-way write conflicts),
//      defer-max (THR=8), setprio around MFMA clusters.

#define DIMC 512
#define HEADS 8
#define HD 32
#define KSZ 7
#define HH 48
#define WW 48
#define BB 2
#define NPIX (HH * WW)         // 2304
#define ROWS (BB * NPIX)       // 4608
#define C3 (3 * DIMC)          // 1536
#define TK 32                  // flash key tile
#define KSPLIT 4
#define KCHUNK (NPIX / KSPLIT) // 576
#define NTILES (KCHUNK / TK)   // 18
#define QB 128                 // queries per block (32 per wave)
#define NQBLK (NPIX / QB)      // 18
#define ROWE 40                // LDS row stride bf16 (80B: 16B-aligned, 2-way banks)
#define VROWE 232              // na Vt row stride

typedef __attribute__((ext_vector_type(8))) short short8;
typedef __attribute__((ext_vector_type(4))) float f32x4;
union frag8 { short8 s; uint32_t u[4]; };

static __device__ __forceinline__ float bf2f(uint32_t u) {
    return __builtin_bit_cast(float, u << 16);
}
static __device__ __forceinline__ uint16_t f2bf(float f) {
    uint32_t x = __builtin_bit_cast(uint32_t, f);
    uint32_t r = x + 0x7fffu + ((x >> 16) & 1u);
    return (uint16_t)(r >> 16);
}
static __device__ __forceinline__ uint32_t cvtpk(float lo, float hi) {
    uint32_t r;
    asm("v_cvt_pk_bf16_f32 %0, %1, %2" : "=v"(r) : "v"(lo), "v"(hi));
    return r;
}

// ---------------- W[K][N] fp32 -> Wt[N][K] bf16
__global__ __launch_bounds__(256)
void transpose_to_bf16(const float* __restrict__ W, uint16_t* __restrict__ Wt,
                       int K, int N)
{
    __shared__ float tile[32][33];
    const int tx = threadIdx.x & 31, ty = threadIdx.x >> 5;
    const int k0 = blockIdx.x * 32, n0 = blockIdx.y * 32;
    #pragma unroll
    for (int i = 0; i < 4; ++i)
        tile[ty + 8 * i][tx] = W[(size_t)(k0 + ty + 8 * i) * N + n0 + tx];
    __syncthreads();
    #pragma unroll
    for (int i = 0; i < 4; ++i)
        Wt[(size_t)(n0 + ty + 8 * i) * K + k0 + tx] = f2bf(tile[tx][ty + 8 * i]);
}

// ---------------- MFMA GEMM: C[M,N] = A[M][K] * Bt_bf16[N][K]^T + bias
template<bool A_F32, bool OUT_F32>
__global__ __launch_bounds__(256)
void gemm_mfma(const void* __restrict__ Av, const uint16_t* __restrict__ Bt,
               const float* __restrict__ bias, void* __restrict__ Cv,
               int M, int N, int K)
{
    constexpr int BM = 128, BK = 32;
    __shared__ __align__(16) uint16_t Al[BM * ROWE];
    __shared__ __align__(16) uint16_t Bl[BM * ROWE];
    const int tid = threadIdx.x;
    const int lane = tid & 63, wv = tid >> 6;
    const int c = lane & 15, g = lane >> 4;
    const int wr = wv >> 1, wc = wv & 1;
    const int m0 = blockIdx.y * BM, n0 = blockIdx.x * BM;
    const int srow = tid >> 2, skc = (tid & 3) * 8;

    f32x4 acc[4][4];
    #pragma unroll
    for (int mi = 0; mi < 4; ++mi)
        #pragma unroll
        for (int ni = 0; ni < 4; ++ni)
            acc[mi][ni] = (f32x4){0.f, 0.f, 0.f, 0.f};

    for (int k0 = 0; k0 < K; k0 += BK) {
        __syncthreads();
        #pragma unroll
        for (int half = 0; half < 2; ++half) {
            const int row = srow + half * 64;
            if (A_F32) {
                const float* A32 = (const float*)Av;
                const float4 a0 = *reinterpret_cast<const float4*>(&A32[(size_t)(m0 + row) * K + k0 + skc]);
                const float4 a1 = *reinterpret_cast<const float4*>(&A32[(size_t)(m0 + row) * K + k0 + skc + 4]);
                *reinterpret_cast<uint4*>(&Al[row * ROWE + skc]) =
                    make_uint4(cvtpk(a0.x, a0.y), cvtpk(a0.z, a0.w),
                               cvtpk(a1.x, a1.y), cvtpk(a1.z, a1.w));
            } else {
                const uint16_t* A16 = (const uint16_t*)Av;
                *reinterpret_cast<uint4*>(&Al[row * ROWE + skc]) =
                    *reinterpret_cast<const uint4*>(&A16[(size_t)(m0 + row) * K + k0 + skc]);
            }
            *reinterpret_cast<uint4*>(&Bl[row * ROWE + skc]) =
                *reinterpret_cast<const uint4*>(&Bt[(size_t)(n0 + row) * K + k0 + skc]);
        }
        __syncthreads();

        frag8 a[4], b[4];
        #pragma unroll
        for (int mi = 0; mi < 4; ++mi)
            a[mi].s = *reinterpret_cast<const short8*>(&Al[(wr * 64 + mi * 16 + c) * ROWE + g * 8]);
        #pragma unroll
        for (int ni = 0; ni < 4; ++ni)
            b[ni].s = *reinterpret_cast<const short8*>(&Bl[(wc * 64 + ni * 16 + c) * ROWE + g * 8]);
        #pragma unroll
        for (int mi = 0; mi < 4; ++mi)
            #pragma unroll
            for (int ni = 0; ni < 4; ++ni)
                acc[mi][ni] = __builtin_amdgcn_mfma_f32_16x16x32_bf16(
                    a[mi].s, b[ni].s, acc[mi][ni], 0, 0, 0);
    }

    #pragma unroll
    for (int mi = 0; mi < 4; ++mi) {
        #pragma unroll
        for (int ni = 0; ni < 4; ++ni) {
            const int row = m0 + wr * 64 + mi * 16 + 4 * g;
            const int col = n0 + wc * 64 + ni * 16 + c;
            const float bv = bias[col];
            #pragma unroll
            for (int r = 0; r < 4; ++r) {
                const float val = acc[mi][ni][r] + bv;
                if (OUT_F32)
                    ((float*)Cv)[(size_t)(row + r) * N + col] = val;
                else
                    ((uint16_t*)Cv)[(size_t)(row + r) * N + col] = f2bf(val);
            }
        }
    }
}

// ---------------- Tile-MFMA neighborhood attention (unchanged from r10)
__global__ __launch_bounds__(256)
void na_attn_mfma(const uint16_t* __restrict__ qkv, const float* __restrict__ rpb,
                  uint16_t* __restrict__ attn)
{
    const int tid = threadIdx.x;
    const int lane = tid & 63, wv = tid >> 6;
    const int c = lane & 15, g = lane >> 4, g4 = g * 4;
    const int bid = blockIdx.x;
    const int tile = bid % 36;
    const int bh = bid / 36;
    const int h = bh & (HEADS - 1), b = bh >> 3;
    const int t0i = (tile / 6) * 8, t0j = (tile % 6) * 8;
    const int u0i = min(max(t0i - 3, 0), HH - 14);
    const int u0j = min(max(t0j - 3, 0), WW - 14);
    const size_t rowbase = (size_t)b * NPIX;
    const float scale = 0.17677669529663687f;

    __shared__ __align__(16) uint16_t K_l[224 * ROWE];
    __shared__ __align__(16) uint16_t Vt[32 * VROWE];
    __shared__ float rpb_l[169];

    if (tid < 169) rpb_l[tid] = rpb[h * 169 + tid];
    #pragma unroll
    for (int it = 0; it < 4; ++it) {
        const int idx = it * 256 + tid;
        if (idx < 896) {
            const int u = idx >> 2, dc = idx & 3;
            const int uc = u & 15, ur = u >> 4;
            if (uc < 14) {
                const int grow = (u0i + ur) * WW + (u0j + uc);
                const uint16_t* src = qkv + (rowbase + grow) * C3 + 256 + h * HD + dc * 8;
                *reinterpret_cast<uint4*>(&K_l[u * ROWE + dc * 8]) =
                    *reinterpret_cast<const uint4*>(src);
                const uint4 vw = *reinterpret_cast<const uint4*>(src + 256);
                const uint16_t* vh = reinterpret_cast<const uint16_t*>(&vw);
                #pragma unroll
                for (int i = 0; i < 8; ++i)
                    Vt[(dc * 8 + i) * VROWE + u] = vh[i];
            } else {
                *reinterpret_cast<uint4*>(&K_l[u * ROWE + dc * 8]) = make_uint4(0, 0, 0, 0);
                #pragma unroll
                for (int i = 0; i < 8; ++i)
                    Vt[(dc * 8 + i) * VROWE + u] = 0;
            }
        }
    }

    const int qid = wv * 16 + c;
    const int qi = t0i + (qid >> 3), qj = t0j + (qid & 7);
    const int pixq = qi * WW + qj;
    const int niq = min(max(qi - 3, 0), HH - KSZ);
    const int njq = min(max(qj - 3, 0), WW - KSZ);
    const int piq = 3 + max(3 - qi, 0) + ((qi + 3 >= HH) ? (HH - qi - 4) : 0);
    const int pjq = 3 + max(3 - qj, 0) + ((qj + 3 >= WW) ? (WW - qj - 4) : 0);
    const int ni_rel = niq - u0i, nj_rel = njq - u0j;
    const int bb = (piq - ni_rel) * 13 + (pjq - nj_rel);

    frag8 qf;
    qf.s = *reinterpret_cast<const short8*>(qkv + (rowbase + pixq) * C3 + h * HD + g * 8);

    __syncthreads();

    float pex[14][4];
    float m = -1e30f;
    #pragma unroll
    for (int f = 0; f < 14; ++f) {
        frag8 ka;
        ka.s = *reinterpret_cast<const short8*>(&K_l[(16 * f + c) * ROWE + g * 8]);
        f32x4 s = {0.f, 0.f, 0.f, 0.f};
        s = __builtin_amdgcn_mfma_f32_16x16x32_bf16(ka.s, qf.s, s, 0, 0, 0);
        const bool rok = (unsigned)(f - ni_rel) < 7u;
        #pragma unroll
        for (int r = 0; r < 4; ++r) {
            const int uc = g4 + r;
            const bool ok = rok && ((unsigned)(uc - nj_rel) < 7u);
            const int addr = ok ? (bb + 13 * f + uc) : 0;
            const float v = s[r] * scale + rpb_l[addr];
            pex[f][r] = ok ? v : -1e30f;
            m = fmaxf(m, pex[f][r]);
        }
    }
    m = fmaxf(m, __shfl_xor(m, 16));
    m = fmaxf(m, __shfl_xor(m, 32));
    float l = 0.f;
    #pragma unroll
    for (int f = 0; f < 14; ++f)
        #pragma unroll
        for (int r = 0; r < 4; ++r) {
            pex[f][r] = __expf(pex[f][r] - m);
            l += pex[f][r];
        }
    l += __shfl_xor(l, 16);
    l += __shfl_xor(l, 32);

    f32x4 of0 = {0.f, 0.f, 0.f, 0.f}, of1 = {0.f, 0.f, 0.f, 0.f};
    const int sbase = (g & 1) * 32 + c;
    #pragma unroll
    for (int kk = 0; kk < 7; ++kk) {
        uint32_t pk0[2], pk1[2];
        pk0[0] = cvtpk(pex[2 * kk][0], pex[2 * kk][1]);
        pk0[1] = cvtpk(pex[2 * kk][2], pex[2 * kk][3]);
        pk1[0] = cvtpk(pex[2 * kk + 1][0], pex[2 * kk + 1][1]);
        pk1[1] = cvtpk(pex[2 * kk + 1][2], pex[2 * kk + 1][3]);
        frag8 pb;
        #pragma unroll
        for (int tt = 0; tt < 4; ++tt) {
            const int srcLane = sbase + ((tt >> 1) << 4);
            const uint32_t v0 = __shfl(pk0[tt & 1], srcLane);
            const uint32_t v1 = __shfl(pk1[tt & 1], srcLane);
            pb.u[tt] = (g >= 2) ? v1 : v0;
        }
        frag8 va0, va1;
        va0.s = *reinterpret_cast<const short8*>(&Vt[c * VROWE + kk * 32 + g * 8]);
        va1.s = *reinterpret_cast<const short8*>(&Vt[(16 + c) * VROWE + kk * 32 + g * 8]);
        of0 = __builtin_amdgcn_mfma_f32_16x16x32_bf16(va0.s, pb.s, of0, 0, 0, 0);
        of1 = __builtin_amdgcn_mfma_f32_16x16x32_bf16(va1.s, pb.s, of1, 0, 0, 0);
    }

    const float invl = 1.f / l;
    uint32_t* dst = reinterpret_cast<uint32_t*>(attn + (rowbase + pixq) * DIMC + h * HD);
    dst[2 * g + 0] = cvtpk(of0[0] * invl, of0[1] * invl);
    dst[2 * g + 1] = cvtpk(of0[2] * invl, of0[3] * invl);
    dst[8 + 2 * g + 0] = cvtpk(of1[0] * invl, of1[1] * invl);
    dst[8 + 2 * g + 1] = cvtpk(of1[2] * invl, of1[3] * invl);
}

// ---------------- MFMA flash self-attention v4: 32 q/wave, swizzled Vt,
// defer-max, setprio. Block = (bh, 128 queries, 1 split of 576 keys).
__global__ __launch_bounds__(256)
void self_attn_flash(const uint16_t* __restrict__ qkv,
                     uint16_t* __restrict__ po, float2* __restrict__ pml)
{
    const int tid = threadIdx.x;
    const int lane = tid & 63, wv = tid >> 6;
    const int c = lane & 15, g = lane >> 4;
    const int bid = blockIdx.x;               // [bh][qblk][split]
    const int split = bid & (KSPLIT - 1);
    const int qblk = (bid >> 2) % NQBLK;
    const int bh = bid / (KSPLIT * NQBLK);
    const int h = bh & (HEADS - 1);
    const int b = bh >> 3;
    const size_t rowbase = (size_t)b * NPIX;
    const int qbase = qblk * QB + wv * 32;
    const int q0 = qbase + c, q1 = qbase + 16 + c;
    const float scale = 0.17677669529663687f;

    __shared__ __align__(16) uint16_t Ks[2][TK * ROWE];
    __shared__ __align__(16) uint16_t Vt[2][TK * ROWE];

    frag8 qf0, qf1;
    qf0.s = *reinterpret_cast<const short8*>(qkv + (rowbase + q0) * C3 + 768 + h * HD + g * 8);
    qf1.s = *reinterpret_cast<const short8*>(qkv + (rowbase + q1) * C3 + 768 + h * HD + g * 8);

    float m0 = -1e30f, m1 = -1e30f, l0 = 0.f, l1 = 0.f;
    f32x4 oa00 = {0,0,0,0}, oa01 = {0,0,0,0};   // q-frag0: d 0..15 / 16..31
    f32x4 oa10 = {0,0,0,0}, oa11 = {0,0,0,0};   // q-frag1

    const int skey = tid >> 3, sdc = tid & 7;
    const int swx = sdc >> 1;                    // (d>>3) for d = sdc*4+i
    const int skw = skey ^ (swx << 3);           // swizzled key slot

    {   // prologue: stage tile 0
        const uint16_t* kp = qkv + (rowbase + split * KCHUNK + skey) * C3 + 1024 + h * HD + sdc * 4;
        const uint2 kw = *reinterpret_cast<const uint2*>(kp);
        const uint2 vw = *reinterpret_cast<const uint2*>(kp + 256);
        *reinterpret_cast<uint2*>(&Ks[0][skey * ROWE + sdc * 4]) = kw;
        Vt[0][(sdc * 4 + 0) * ROWE + skw] = (uint16_t)(vw.x & 0xffffu);
        Vt[0][(sdc * 4 + 1) * ROWE + skw] = (uint16_t)(vw.x >> 16);
        Vt[0][(sdc * 4 + 2) * ROWE + skw] = (uint16_t)(vw.y & 0xffffu);
        Vt[0][(sdc * 4 + 3) * ROWE + skw] = (uint16_t)(vw.y >> 16);
    }

    // swizzled V-read offsets (row d=c and d=16+c)
    const int vro0 = c * ROWE + ((g ^ (c >> 3)) << 3);
    const int vro1 = (16 + c) * ROWE + ((g ^ ((2 + (c >> 3)) & 3)) << 3);
    const int sbase = (g & 1) * 32 + c;

    for (int t = 0; t < NTILES; ++t) {
        __syncthreads();

        uint2 nk, nv;
        const bool more = (t + 1 < NTILES);
        if (more) {   // T14: issue early
            const uint16_t* kp = qkv + (rowbase + split * KCHUNK + (t + 1) * TK + skey) * C3
                                 + 1024 + h * HD + sdc * 4;
            nk = *reinterpret_cast<const uint2*>(kp);
            nv = *reinterpret_cast<const uint2*>(kp + 256);
        }

        const int cur = t & 1;
        frag8 ka0, ka1;
        ka0.s = *reinterpret_cast<const short8*>(&Ks[cur][c * ROWE + g * 8]);
        ka1.s = *reinterpret_cast<const short8*>(&Ks[cur][(16 + c) * ROWE + g * 8]);
        f32x4 s00 = {0,0,0,0}, s01 = {0,0,0,0}, s10 = {0,0,0,0}, s11 = {0,0,0,0};
        __builtin_amdgcn_s_setprio(1);
        s00 = __builtin_amdgcn_mfma_f32_16x16x32_bf16(ka0.s, qf0.s, s00, 0, 0, 0);
        s01 = __builtin_amdgcn_mfma_f32_16x16x32_bf16(ka1.s, qf0.s, s01, 0, 0, 0);
        s10 = __builtin_amdgcn_mfma_f32_16x16x32_bf16(ka0.s, qf1.s, s10, 0, 0, 0);
        s11 = __builtin_amdgcn_mfma_f32_16x16x32_bf16(ka1.s, qf1.s, s11, 0, 0, 0);
        __builtin_amdgcn_s_setprio(0);

        float p0[8] = {s00[0] * scale, s00[1] * scale, s00[2] * scale, s00[3] * scale,
                       s01[0] * scale, s01[1] * scale, s01[2] * scale, s01[3] * scale};
        float p1[8] = {s10[0] * scale, s10[1] * scale, s10[2] * scale, s10[3] * scale,
                       s11[0] * scale, s11[1] * scale, s11[2] * scale, s11[3] * scale};
        float t0 = fmaxf(fmaxf(fmaxf(p0[0], p0[1]), fmaxf(p0[2], p0[3])),
                         fmaxf(fmaxf(p0[4], p0[5]), fmaxf(p0[6], p0[7])));
        float t1 = fmaxf(fmaxf(fmaxf(p1[0], p1[1]), fmaxf(p1[2], p1[3])),
                         fmaxf(fmaxf(p1[4], p1[5]), fmaxf(p1[6], p1[7])));
        t0 = fmaxf(t0, __shfl_xor(t0, 16)); t0 = fmaxf(t0, __shfl_xor(t0, 32));
        t1 = fmaxf(t1, __shfl_xor(t1, 16)); t1 = fmaxf(t1, __shfl_xor(t1, 32));

        // defer-max (T13): only rescale when some col grew past THR=8
        const int ok = (t0 - m0 <= 8.f) && (t1 - m1 <= 8.f);
        if (!__all(ok)) {
            const float nm0 = fmaxf(m0, t0), nm1 = fmaxf(m1, t1);
            const float c0 = __expf(m0 - nm0), c1 = __expf(m1 - nm1);
            l0 *= c0; l1 *= c1;
            oa00 *= c0; oa01 *= c0; oa10 *= c1; oa11 *= c1;
            m0 = nm0; m1 = nm1;
        }

        float sum0 = 0.f, sum1 = 0.f;
        #pragma unroll
        for (int j = 0; j < 8; ++j) { p0[j] = __expf(p0[j] - m0); sum0 += p0[j]; }
        #pragma unroll
        for (int j = 0; j < 8; ++j) { p1[j] = __expf(p1[j] - m1); sum1 += p1[j]; }
        sum0 += __shfl_xor(sum0, 16); sum0 += __shfl_xor(sum0, 32);
        sum1 += __shfl_xor(sum1, 16); sum1 += __shfl_xor(sum1, 32);
        l0 += sum0; l1 += sum1;

        uint32_t pk00[2], pk01[2], pk10[2], pk11[2];
        pk00[0] = cvtpk(p0[0], p0[1]); pk00[1] = cvtpk(p0[2], p0[3]);
        pk01[0] = cvtpk(p0[4], p0[5]); pk01[1] = cvtpk(p0[6], p0[7]);
        pk10[0] = cvtpk(p1[0], p1[1]); pk10[1] = cvtpk(p1[2], p1[3]);
        pk11[0] = cvtpk(p1[4], p1[5]); pk11[1] = cvtpk(p1[6], p1[7]);

        frag8 pb0, pb1;
        #pragma unroll
        for (int tt = 0; tt < 4; ++tt) {
            const int srcLane = sbase + ((tt >> 1) << 4);
            const uint32_t a0 = __shfl(pk00[tt & 1], srcLane);
            const uint32_t a1 = __shfl(pk01[tt & 1], srcLane);
            pb0.u[tt] = (g >= 2) ? a1 : a0;
            const uint32_t b0 = __shfl(pk10[tt & 1], srcLane);
            const uint32_t b1 = __shfl(pk11[tt & 1], srcLane);
            pb1.u[tt] = (g >= 2) ? b1 : b0;
        }

        frag8 va0, va1;
        va0.s = *reinterpret_cast<const short8*>(&Vt[cur][vro0]);
        va1.s = *reinterpret_cast<const short8*>(&Vt[cur][vro1]);
        __builtin_amdgcn_s_setprio(1);
        oa00 = __builtin_amdgcn_mfma_f32_16x16x32_bf16(va0.s, pb0.s, oa00, 0, 0, 0);
        oa01 = __builtin_amdgcn_mfma_f32_16x16x32_bf16(va1.s, pb0.s, oa01, 0, 0, 0);
        oa10 = __builtin_amdgcn_mfma_f32_16x16x32_bf16(va0.s, pb1.s, oa10, 0, 0, 0);
        oa11 = __builtin_amdgcn_mfma_f32_16x16x32_bf16(va1.s, pb1.s, oa11, 0, 0, 0);
        __builtin_amdgcn_s_setprio(0);

        if (more) {   // write late
            const int nxt = cur ^ 1;
            *reinterpret_cast<uint2*>(&Ks[nxt][skey * ROWE + sdc * 4]) = nk;
            Vt[nxt][(sdc * 4 + 0) * ROWE + skw] = (uint16_t)(nv.x & 0xffffu);
            Vt[nxt][(sdc * 4 + 1) * ROWE + skw] = (uint16_t)(nv.x >> 16);
            Vt[nxt][(sdc * 4 + 2) * ROWE + skw] = (uint16_t)(nv.y & 0xffffu);
            Vt[nxt][(sdc * 4 + 3) * ROWE + skw] = (uint16_t)(nv.y >> 16);
        }
    }

    const float i0 = 1.f / l0, i1 = 1.f / l1;
    const size_t item0 = ((size_t)split * 16 + bh) * NPIX + q0;
    const size_t item1 = ((size_t)split * 16 + bh) * NPIX + q1;
    uint32_t* d0 = reinterpret_cast<uint32_t*>(po + item0 * HD);
    d0[2 * g + 0] = cvtpk(oa00[0] * i0, oa00[1] * i0);
    d0[2 * g + 1] = cvtpk(oa00[2] * i0, oa00[3] * i0);
    d0[8 + 2 * g + 0] = cvtpk(oa01[0] * i0, oa01[1] * i0);
    d0[8 + 2 * g + 1] = cvtpk(oa01[2] * i0, oa01[3] * i0);
    uint32_t* d1 = reinterpret_cast<uint32_t*>(po + item1 * HD);
    d1[2 * g + 0] = cvtpk(oa10[0] * i1, oa10[1] * i1);
    d1[2 * g + 1] = cvtpk(oa10[2] * i1, oa10[3] * i1);
    d1[8 + 2 * g + 0] = cvtpk(oa11[0] * i1, oa11[1] * i1);
    d1[8 + 2 * g + 1] = cvtpk(oa11[2] * i1, oa11[3] * i1);
    if (g == 0) {
        pml[item0] = make_float2(m0, l0);
        pml[item1] = make_float2(m1, l1);
    }
}

// ---------------- Combine split-K partials -> attn[:, 256:512) bf16
__global__ __launch_bounds__(256)
void self_attn_combine(const uint16_t* __restrict__ po, const float2* __restrict__ pml,
                       uint16_t* __restrict__ attn)
{
    const int idx = blockIdx.x * 256 + threadIdx.x;
    const int d = idx & (HD - 1);
    const int q = (idx >> 5) % NPIX;
    const int bh = idx / (HD * NPIX);
    const int h = bh & (HEADS - 1);
    const int b = bh >> 3;

    float2 ml[KSPLIT];
    float M = -1e30f;
    #pragma unroll
    for (int s = 0; s < KSPLIT; ++s) {
        ml[s] = pml[((size_t)s * 16 + bh) * NPIX + q];
        M = fmaxf(M, ml[s].x);
    }
    float num = 0.f, den = 0.f;
    #pragma unroll
    for (int s = 0; s < KSPLIT; ++s) {
        const float w = __expf(ml[s].x - M) * ml[s].y;
        const float o = bf2f((uint32_t)po[(((size_t)s * 16 + bh) * NPIX + q) * HD + d]);
        num = fmaf(w, o, num);
        den += w;
    }
    attn[((size_t)b * NPIX + q) * DIMC + 256 + h * HD + d] = f2bf(num / den);
}

extern "C" void kernel_launch(void* const* d_in, const int* in_sizes, int n_in,
                              void* d_out, int out_size, void* d_ws, size_t ws_size,
                              hipStream_t stream)
{
    const float* x     = (const float*)d_in[0];
    const float* Wqkv  = (const float*)d_in[1];
    const float* bqkv  = (const float*)d_in[2];
    const float* rpb   = (const float*)d_in[3];
    const float* Wproj = (const float*)d_in[4];
    const float* bproj = (const float*)d_in[5];

    uint16_t* qkv  = (uint16_t*)d_ws;                     // [ROWS][C3]   14.2 MB
    uint16_t* attn = qkv + (size_t)ROWS * C3;             // [ROWS][DIMC]  4.7 MB
    uint16_t* wqt  = attn + (size_t)ROWS * DIMC;          // [C3][DIMC]    1.6 MB
    uint16_t* wpt  = wqt + (size_t)C3 * DIMC;             // [DIMC][DIMC]  0.5 MB
    float2*   pml  = (float2*)(wpt + (size_t)DIMC * DIMC);// 4*16*NPIX     1.2 MB
    uint16_t* po   = (uint16_t*)d_out;                    // partial scratch (dead until gemm2)

    const dim3 blk(256);
    transpose_to_bf16<<<dim3(DIMC / 32, C3 / 32), blk, 0, stream>>>(Wqkv, wqt, DIMC, C3);
    transpose_to_bf16<<<dim3(DIMC / 32, DIMC / 32), blk, 0, stream>>>(Wproj, wpt, DIMC, DIMC);
    gemm_mfma<true, false><<<dim3(C3 / 128, ROWS / 128), blk, 0, stream>>>(
        x, wqt, bqkv, qkv, ROWS, C3, DIMC);
    na_attn_mfma<<<dim3(BB * HEADS * 36), blk, 0, stream>>>(qkv, rpb, attn);
    self_attn_flash<<<dim3(16 * NQBLK * KSPLIT), blk, 0, stream>>>(qkv, po, pml);
    self_attn_combine<<<dim3((16 * NPIX * HD) / 256), blk, 0, stream>>>(po, pml, attn);
    gemm_mfma<false, true><<<dim3(DIMC / 128, ROWS / 128), blk, 0, stream>>>(
        attn, wpt, bproj, d_out, ROWS, DIMC, DIMC);
}

// Round 12
// 105.768 us; speedup vs baseline: 7.9460x; 1.0660x over previous
//
#include <hip/hip_runtime.h>
#include <cstdint>
#include <cstddef>

// MixedAttention: transpose-W -> MFMA qkv GEMM (fused f32->bf16, Q prescaled by
// scale*log2e in epilogue) -> {tile-MFMA na attn | MFMA flash self attn, both
// exp2-domain softmax} -> MFMA proj GEMM.
// r12: flash TK=64 (9 tiles), exp2 softmax, deferred l-reduce, defer-max log2.

#define DIMC 512
#define HEADS 8
#define HD 32
#define KSZ 7
#define HH 48
#define WW 48
#define BB 2
#define NPIX (HH * WW)         // 2304
#define ROWS (BB * NPIX)       // 4608
#define C3 (3 * DIMC)          // 1536
#define TK 64                  // flash key tile
#define KSPLIT 4
#define KCHUNK (NPIX / KSPLIT) // 576
#define NTILES (KCHUNK / TK)   // 9
#define QB 128                 // queries per block (32 per wave)
#define NQBLK (NPIX / QB)      // 18
#define ROWE 40                // K LDS row stride bf16 (80B)
#define VSTR 80                // flash Vt row stride bf16 (64 keys + 16 pad)
#define VROWE 232              // na Vt row stride
#define LOG2E 1.4426950408889634f

typedef __attribute__((ext_vector_type(8))) short short8;
typedef __attribute__((ext_vector_type(4))) float f32x4;
union frag8 { short8 s; uint32_t u[4]; };

static __device__ __forceinline__ float bf2f(uint32_t u) {
    return __builtin_bit_cast(float, u << 16);
}
static __device__ __forceinline__ uint16_t f2bf(float f) {
    uint32_t x = __builtin_bit_cast(uint32_t, f);
    uint32_t r = x + 0x7fffu + ((x >> 16) & 1u);
    return (uint16_t)(r >> 16);
}
static __device__ __forceinline__ uint32_t cvtpk(float lo, float hi) {
    uint32_t r;
    asm("v_cvt_pk_bf16_f32 %0, %1, %2" : "=v"(r) : "v"(lo), "v"(hi));
    return r;
}
static __device__ __forceinline__ float ex2(float x) {
    return __builtin_amdgcn_exp2f(x);
}

// ---------------- W[K][N] fp32 -> Wt[N][K] bf16
__global__ __launch_bounds__(256)
void transpose_to_bf16(const float* __restrict__ W, uint16_t* __restrict__ Wt,
                       int K, int N)
{
    __shared__ float tile[32][33];
    const int tx = threadIdx.x & 31, ty = threadIdx.x >> 5;
    const int k0 = blockIdx.x * 32, n0 = blockIdx.y * 32;
    #pragma unroll
    for (int i = 0; i < 4; ++i)
        tile[ty + 8 * i][tx] = W[(size_t)(k0 + ty + 8 * i) * N + n0 + tx];
    __syncthreads();
    #pragma unroll
    for (int i = 0; i < 4; ++i)
        Wt[(size_t)(n0 + ty + 8 * i) * K + k0 + tx] = f2bf(tile[tx][ty + 8 * i]);
}

// ---------------- MFMA GEMM: C[M,N] = A[M][K] * Bt_bf16[N][K]^T + bias
// QSCALE: multiply (acc+bias) by scale*log2e on Q-channel columns.
template<bool A_F32, bool OUT_F32, bool QSCALE>
__global__ __launch_bounds__(256)
void gemm_mfma(const void* __restrict__ Av, const uint16_t* __restrict__ Bt,
               const float* __restrict__ bias, void* __restrict__ Cv,
               int M, int N, int K)
{
    constexpr int BM = 128, BK = 32;
    constexpr float QSC = 0.17677669529663687f * LOG2E;
    __shared__ __align__(16) uint16_t Al[BM * ROWE];
    __shared__ __align__(16) uint16_t Bl[BM * ROWE];
    const int tid = threadIdx.x;
    const int lane = tid & 63, wv = tid >> 6;
    const int c = lane & 15, g = lane >> 4;
    const int wr = wv >> 1, wc = wv & 1;
    const int m0 = blockIdx.y * BM, n0 = blockIdx.x * BM;
    const int srow = tid >> 2, skc = (tid & 3) * 8;

    f32x4 acc[4][4];
    #pragma unroll
    for (int mi = 0; mi < 4; ++mi)
        #pragma unroll
        for (int ni = 0; ni < 4; ++ni)
            acc[mi][ni] = (f32x4){0.f, 0.f, 0.f, 0.f};

    for (int k0 = 0; k0 < K; k0 += BK) {
        __syncthreads();
        #pragma unroll
        for (int half = 0; half < 2; ++half) {
            const int row = srow + half * 64;
            if (A_F32) {
                const float* A32 = (const float*)Av;
                const float4 a0 = *reinterpret_cast<const float4*>(&A32[(size_t)(m0 + row) * K + k0 + skc]);
                const float4 a1 = *reinterpret_cast<const float4*>(&A32[(size_t)(m0 + row) * K + k0 + skc + 4]);
                *reinterpret_cast<uint4*>(&Al[row * ROWE + skc]) =
                    make_uint4(cvtpk(a0.x, a0.y), cvtpk(a0.z, a0.w),
                               cvtpk(a1.x, a1.y), cvtpk(a1.z, a1.w));
            } else {
                const uint16_t* A16 = (const uint16_t*)Av;
                *reinterpret_cast<uint4*>(&Al[row * ROWE + skc]) =
                    *reinterpret_cast<const uint4*>(&A16[(size_t)(m0 + row) * K + k0 + skc]);
            }
            *reinterpret_cast<uint4*>(&Bl[row * ROWE + skc]) =
                *reinterpret_cast<const uint4*>(&Bt[(size_t)(n0 + row) * K + k0 + skc]);
        }
        __syncthreads();

        frag8 a[4], b[4];
        #pragma unroll
        for (int mi = 0; mi < 4; ++mi)
            a[mi].s = *reinterpret_cast<const short8*>(&Al[(wr * 64 + mi * 16 + c) * ROWE + g * 8]);
        #pragma unroll
        for (int ni = 0; ni < 4; ++ni)
            b[ni].s = *reinterpret_cast<const short8*>(&Bl[(wc * 64 + ni * 16 + c) * ROWE + g * 8]);
        #pragma unroll
        for (int mi = 0; mi < 4; ++mi)
            #pragma unroll
            for (int ni = 0; ni < 4; ++ni)
                acc[mi][ni] = __builtin_amdgcn_mfma_f32_16x16x32_bf16(
                    a[mi].s, b[ni].s, acc[mi][ni], 0, 0, 0);
    }

    #pragma unroll
    for (int mi = 0; mi < 4; ++mi) {
        #pragma unroll
        for (int ni = 0; ni < 4; ++ni) {
            const int row = m0 + wr * 64 + mi * 16 + 4 * g;
            const int col = n0 + wc * 64 + ni * 16 + c;
            const float bv = bias[col];
            float f = 1.f;
            if (QSCALE) f = (col < 256 || (col >= 768 && col < 1024)) ? QSC : 1.f;
            #pragma unroll
            for (int r = 0; r < 4; ++r) {
                const float val = (acc[mi][ni][r] + bv) * f;
                if (OUT_F32)
                    ((float*)Cv)[(size_t)(row + r) * N + col] = val;
                else
                    ((uint16_t*)Cv)[(size_t)(row + r) * N + col] = f2bf(val);
            }
        }
    }
}

// ---------------- Tile-MFMA neighborhood attention (exp2 domain; Q prescaled)
__global__ __launch_bounds__(256)
void na_attn_mfma(const uint16_t* __restrict__ qkv, const float* __restrict__ rpb,
                  uint16_t* __restrict__ attn)
{
    const int tid = threadIdx.x;
    const int lane = tid & 63, wv = tid >> 6;
    const int c = lane & 15, g = lane >> 4, g4 = g * 4;
    const int bid = blockIdx.x;
    const int tile = bid % 36;
    const int bh = bid / 36;
    const int h = bh & (HEADS - 1), b = bh >> 3;
    const int t0i = (tile / 6) * 8, t0j = (tile % 6) * 8;
    const int u0i = min(max(t0i - 3, 0), HH - 14);
    const int u0j = min(max(t0j - 3, 0), WW - 14);
    const size_t rowbase = (size_t)b * NPIX;

    __shared__ __align__(16) uint16_t K_l[224 * ROWE];
    __shared__ __align__(16) uint16_t Vt[32 * VROWE];
    __shared__ float rpb_l[169];

    if (tid < 169) rpb_l[tid] = rpb[h * 169 + tid] * LOG2E;
    #pragma unroll
    for (int it = 0; it < 4; ++it) {
        const int idx = it * 256 + tid;
        if (idx < 896) {
            const int u = idx >> 2, dc = idx & 3;
            const int uc = u & 15, ur = u >> 4;
            if (uc < 14) {
                const int grow = (u0i + ur) * WW + (u0j + uc);
                const uint16_t* src = qkv + (rowbase + grow) * C3 + 256 + h * HD + dc * 8;
                *reinterpret_cast<uint4*>(&K_l[u * ROWE + dc * 8]) =
                    *reinterpret_cast<const uint4*>(src);
                const uint4 vw = *reinterpret_cast<const uint4*>(src + 256);
                const uint16_t* vh = reinterpret_cast<const uint16_t*>(&vw);
                #pragma unroll
                for (int i = 0; i < 8; ++i)
                    Vt[(dc * 8 + i) * VROWE + u] = vh[i];
            } else {
                *reinterpret_cast<uint4*>(&K_l[u * ROWE + dc * 8]) = make_uint4(0, 0, 0, 0);
                #pragma unroll
                for (int i = 0; i < 8; ++i)
                    Vt[(dc * 8 + i) * VROWE + u] = 0;
            }
        }
    }

    const int qid = wv * 16 + c;
    const int qi = t0i + (qid >> 3), qj = t0j + (qid & 7);
    const int pixq = qi * WW + qj;
    const int niq = min(max(qi - 3, 0), HH - KSZ);
    const int njq = min(max(qj - 3, 0), WW - KSZ);
    const int piq = 3 + max(3 - qi, 0) + ((qi + 3 >= HH) ? (HH - qi - 4) : 0);
    const int pjq = 3 + max(3 - qj, 0) + ((qj + 3 >= WW) ? (WW - qj - 4) : 0);
    const int ni_rel = niq - u0i, nj_rel = njq - u0j;
    const int bb = (piq - ni_rel) * 13 + (pjq - nj_rel);

    frag8 qf;
    qf.s = *reinterpret_cast<const short8*>(qkv + (rowbase + pixq) * C3 + h * HD + g * 8);

    __syncthreads();

    float pex[14][4];
    float m = -1e30f;
    #pragma unroll
    for (int f = 0; f < 14; ++f) {
        frag8 ka;
        ka.s = *reinterpret_cast<const short8*>(&K_l[(16 * f + c) * ROWE + g * 8]);
        f32x4 s = {0.f, 0.f, 0.f, 0.f};
        s = __builtin_amdgcn_mfma_f32_16x16x32_bf16(ka.s, qf.s, s, 0, 0, 0);
        const bool rok = (unsigned)(f - ni_rel) < 7u;
        #pragma unroll
        for (int r = 0; r < 4; ++r) {
            const int uc = g4 + r;
            const bool ok = rok && ((unsigned)(uc - nj_rel) < 7u);
            const int addr = ok ? (bb + 13 * f + uc) : 0;
            const float v = s[r] + rpb_l[addr];       // log2 domain (Q prescaled)
            pex[f][r] = ok ? v : -1e30f;
            m = fmaxf(m, pex[f][r]);
        }
    }
    m = fmaxf(m, __shfl_xor(m, 16));
    m = fmaxf(m, __shfl_xor(m, 32));
    float l = 0.f;
    #pragma unroll
    for (int f = 0; f < 14; ++f)
        #pragma unroll
        for (int r = 0; r < 4; ++r) {
            pex[f][r] = ex2(pex[f][r] - m);
            l += pex[f][r];
        }
    l += __shfl_xor(l, 16);
    l += __shfl_xor(l, 32);

    f32x4 of0 = {0.f, 0.f, 0.f, 0.f}, of1 = {0.f, 0.f, 0.f, 0.f};
    const int sbase = (g & 1) * 32 + c;
    #pragma unroll
    for (int kk = 0; kk < 7; ++kk) {
        uint32_t pk0[2], pk1[2];
        pk0[0] = cvtpk(pex[2 * kk][0], pex[2 * kk][1]);
        pk0[1] = cvtpk(pex[2 * kk][2], pex[2 * kk][3]);
        pk1[0] = cvtpk(pex[2 * kk + 1][0], pex[2 * kk + 1][1]);
        pk1[1] = cvtpk(pex[2 * kk + 1][2], pex[2 * kk + 1][3]);
        frag8 pb;
        #pragma unroll
        for (int tt = 0; tt < 4; ++tt) {
            const int srcLane = sbase + ((tt >> 1) << 4);
            const uint32_t v0 = __shfl(pk0[tt & 1], srcLane);
            const uint32_t v1 = __shfl(pk1[tt & 1], srcLane);
            pb.u[tt] = (g >= 2) ? v1 : v0;
        }
        frag8 va0, va1;
        va0.s = *reinterpret_cast<const short8*>(&Vt[c * VROWE + kk * 32 + g * 8]);
        va1.s = *reinterpret_cast<const short8*>(&Vt[(16 + c) * VROWE + kk * 32 + g * 8]);
        of0 = __builtin_amdgcn_mfma_f32_16x16x32_bf16(va0.s, pb.s, of0, 0, 0, 0);
        of1 = __builtin_amdgcn_mfma_f32_16x16x32_bf16(va1.s, pb.s, of1, 0, 0, 0);
    }

    const float invl = 1.f / l;
    uint32_t* dst = reinterpret_cast<uint32_t*>(attn + (rowbase + pixq) * DIMC + h * HD);
    dst[2 * g + 0] = cvtpk(of0[0] * invl, of0[1] * invl);
    dst[2 * g + 1] = cvtpk(of0[2] * invl, of0[3] * invl);
    dst[8 + 2 * g + 0] = cvtpk(of1[0] * invl, of1[1] * invl);
    dst[8 + 2 * g + 1] = cvtpk(of1[2] * invl, of1[3] * invl);
}

// ---------------- MFMA flash self-attention v5: TK=64, exp2 domain,
// deferred l-reduce, defer-max, swizzled Vt, setprio.
__global__ __launch_bounds__(256)
void self_attn_flash(const uint16_t* __restrict__ qkv,
                     uint16_t* __restrict__ po, float2* __restrict__ pml)
{
    const int tid = threadIdx.x;
    const int lane = tid & 63, wv = tid >> 6;
    const int c = lane & 15, g = lane >> 4;
    const int bid = blockIdx.x;               // [bh][qblk][split]
    const int split = bid & (KSPLIT - 1);
    const int qblk = (bid >> 2) % NQBLK;
    const int bh = bid / (KSPLIT * NQBLK);
    const int h = bh & (HEADS - 1);
    const int b = bh >> 3;
    const size_t rowbase = (size_t)b * NPIX;
    const int qbase = qblk * QB + wv * 32;
    const int q0 = qbase + c, q1 = qbase + 16 + c;

    __shared__ __align__(16) uint16_t Ks[2][TK * ROWE];      // 64 keys x 32d
    __shared__ __align__(16) uint16_t Vt[2][32 * VSTR];      // 32d x 64 keys

    frag8 qf0, qf1;   // Q prescaled by scale*log2e in gemm1
    qf0.s = *reinterpret_cast<const short8*>(qkv + (rowbase + q0) * C3 + 768 + h * HD + g * 8);
    qf1.s = *reinterpret_cast<const short8*>(qkv + (rowbase + q1) * C3 + 768 + h * HD + g * 8);

    float m0 = -1e30f, m1 = -1e30f, ls0 = 0.f, ls1 = 0.f;
    f32x4 oa00 = {0,0,0,0}, oa01 = {0,0,0,0};
    f32x4 oa10 = {0,0,0,0}, oa11 = {0,0,0,0};

    const int skey = tid >> 3;                 // 0..31 (stages keys skey, skey+32)
    const int sdc = tid & 7;
    const int swx = (sdc >> 1) << 3;           // ((d>>3)&3)<<3 for d=4*sdc..+3

#define STAGE_LOAD(T, KW0, VW0, KW1, VW1) do {                                        \
    const uint16_t* _bp = qkv + (rowbase + split * KCHUNK + (T) * TK + skey) * C3     \
                          + 1024 + h * HD + sdc * 4;                                  \
    KW0 = *reinterpret_cast<const uint2*>(_bp);                                       \
    VW0 = *reinterpret_cast<const uint2*>(_bp + 256);                                 \
    KW1 = *reinterpret_cast<const uint2*>(_bp + 32 * C3);                             \
    VW1 = *reinterpret_cast<const uint2*>(_bp + 32 * C3 + 256); } while (0)

#define STAGE_WRITE(BUF, KW0, VW0, KW1, VW1) do {                                     \
    *reinterpret_cast<uint2*>(&Ks[BUF][skey * ROWE + sdc * 4]) = KW0;                 \
    *reinterpret_cast<uint2*>(&Ks[BUF][(skey + 32) * ROWE + sdc * 4]) = KW1;          \
    const int _s0 = skey ^ swx, _s1 = (skey + 32) ^ swx;                              \
    Vt[BUF][(sdc * 4 + 0) * VSTR + _s0] = (uint16_t)(VW0.x & 0xffffu);                \
    Vt[BUF][(sdc * 4 + 1) * VSTR + _s0] = (uint16_t)(VW0.x >> 16);                    \
    Vt[BUF][(sdc * 4 + 2) * VSTR + _s0] = (uint16_t)(VW0.y & 0xffffu);                \
    Vt[BUF][(sdc * 4 + 3) * VSTR + _s0] = (uint16_t)(VW0.y >> 16);                    \
    Vt[BUF][(sdc * 4 + 0) * VSTR + _s1] = (uint16_t)(VW1.x & 0xffffu);                \
    Vt[BUF][(sdc * 4 + 1) * VSTR + _s1] = (uint16_t)(VW1.x >> 16);                    \
    Vt[BUF][(sdc * 4 + 2) * VSTR + _s1] = (uint16_t)(VW1.y & 0xffffu);                \
    Vt[BUF][(sdc * 4 + 3) * VSTR + _s1] = (uint16_t)(VW1.y >> 16); } while (0)

    {   // prologue: stage tile 0 into buf 0
        uint2 kw0, vw0, kw1, vw1;
        STAGE_LOAD(0, kw0, vw0, kw1, vw1);
        STAGE_WRITE(0, kw0, vw0, kw1, vw1);
    }

    const int sbase = (g & 1) * 32 + c;
    const int cr3 = c >> 3;

    for (int t = 0; t < NTILES; ++t) {
        __syncthreads();

        uint2 nk0, nv0, nk1, nv1;
        const bool more = (t + 1 < NTILES);
        if (more) STAGE_LOAD(t + 1, nk0, nv0, nk1, nv1);   // T14: issue early

        const int cur = t & 1;
        frag8 ka0, ka1, ka2, ka3;
        ka0.s = *reinterpret_cast<const short8*>(&Ks[cur][c * ROWE + g * 8]);
        ka1.s = *reinterpret_cast<const short8*>(&Ks[cur][(16 + c) * ROWE + g * 8]);
        ka2.s = *reinterpret_cast<const short8*>(&Ks[cur][(32 + c) * ROWE + g * 8]);
        ka3.s = *reinterpret_cast<const short8*>(&Ks[cur][(48 + c) * ROWE + g * 8]);
        f32x4 sc0[4], sc1[4];
        #pragma unroll
        for (int kf = 0; kf < 4; ++kf) {
            sc0[kf] = (f32x4){0,0,0,0};
            sc1[kf] = (f32x4){0,0,0,0};
        }
        __builtin_amdgcn_s_setprio(1);
        sc0[0] = __builtin_amdgcn_mfma_f32_16x16x32_bf16(ka0.s, qf0.s, sc0[0], 0, 0, 0);
        sc0[1] = __builtin_amdgcn_mfma_f32_16x16x32_bf16(ka1.s, qf0.s, sc0[1], 0, 0, 0);
        sc0[2] = __builtin_amdgcn_mfma_f32_16x16x32_bf16(ka2.s, qf0.s, sc0[2], 0, 0, 0);
        sc0[3] = __builtin_amdgcn_mfma_f32_16x16x32_bf16(ka3.s, qf0.s, sc0[3], 0, 0, 0);
        sc1[0] = __builtin_amdgcn_mfma_f32_16x16x32_bf16(ka0.s, qf1.s, sc1[0], 0, 0, 0);
        sc1[1] = __builtin_amdgcn_mfma_f32_16x16x32_bf16(ka1.s, qf1.s, sc1[1], 0, 0, 0);
        sc1[2] = __builtin_amdgcn_mfma_f32_16x16x32_bf16(ka2.s, qf1.s, sc1[2], 0, 0, 0);
        sc1[3] = __builtin_amdgcn_mfma_f32_16x16x32_bf16(ka3.s, qf1.s, sc1[3], 0, 0, 0);
        __builtin_amdgcn_s_setprio(0);

        // tile max (scores already in log2 domain)
        float t0 = sc0[0][0], t1 = sc1[0][0];
        #pragma unroll
        for (int kf = 0; kf < 4; ++kf)
            #pragma unroll
            for (int r = 0; r < 4; ++r) {
                t0 = fmaxf(t0, sc0[kf][r]);
                t1 = fmaxf(t1, sc1[kf][r]);
            }
        t0 = fmaxf(t0, __shfl_xor(t0, 16)); t0 = fmaxf(t0, __shfl_xor(t0, 32));
        t1 = fmaxf(t1, __shfl_xor(t1, 16)); t1 = fmaxf(t1, __shfl_xor(t1, 32));

        // defer-max (THR = 8*log2e ~ 11.54 in log2 domain)
        const int ok = (t0 - m0 <= 11.54f) && (t1 - m1 <= 11.54f);
        if (!__all(ok)) {
            const float nm0 = fmaxf(m0, t0), nm1 = fmaxf(m1, t1);
            const float c0 = ex2(m0 - nm0), c1 = ex2(m1 - nm1);
            ls0 *= c0; ls1 *= c1;
            oa00 *= c0; oa01 *= c0; oa10 *= c1; oa11 *= c1;
            m0 = nm0; m1 = nm1;
        }

        // exp2 in place + per-lane partial sums (reduced once at end)
        #pragma unroll
        for (int kf = 0; kf < 4; ++kf)
            #pragma unroll
            for (int r = 0; r < 4; ++r) {
                sc0[kf][r] = ex2(sc0[kf][r] - m0); ls0 += sc0[kf][r];
                sc1[kf][r] = ex2(sc1[kf][r] - m1); ls1 += sc1[kf][r];
            }

        // PV: 2 chunks of 32 keys
        #pragma unroll
        for (int kk = 0; kk < 2; ++kk) {
            uint32_t pk00[2], pk01[2], pk10[2], pk11[2];
            pk00[0] = cvtpk(sc0[2 * kk][0], sc0[2 * kk][1]);
            pk00[1] = cvtpk(sc0[2 * kk][2], sc0[2 * kk][3]);
            pk01[0] = cvtpk(sc0[2 * kk + 1][0], sc0[2 * kk + 1][1]);
            pk01[1] = cvtpk(sc0[2 * kk + 1][2], sc0[2 * kk + 1][3]);
            pk10[0] = cvtpk(sc1[2 * kk][0], sc1[2 * kk][1]);
            pk10[1] = cvtpk(sc1[2 * kk][2], sc1[2 * kk][3]);
            pk11[0] = cvtpk(sc1[2 * kk + 1][0], sc1[2 * kk + 1][1]);
            pk11[1] = cvtpk(sc1[2 * kk + 1][2], sc1[2 * kk + 1][3]);

            frag8 pb0, pb1;
            #pragma unroll
            for (int tt = 0; tt < 4; ++tt) {
                const int srcLane = sbase + ((tt >> 1) << 4);
                const uint32_t a0 = __shfl(pk00[tt & 1], srcLane);
                const uint32_t a1 = __shfl(pk01[tt & 1], srcLane);
                pb0.u[tt] = (g >= 2) ? a1 : a0;
                const uint32_t b0 = __shfl(pk10[tt & 1], srcLane);
                const uint32_t b1 = __shfl(pk11[tt & 1], srcLane);
                pb1.u[tt] = (g >= 2) ? b1 : b0;
            }

            frag8 va0, va1;   // swizzled block select: (kk*4+g) ^ (d>>3)
            va0.s = *reinterpret_cast<const short8*>(
                &Vt[cur][c * VSTR + (((kk * 4 + g) ^ cr3) << 3)]);
            va1.s = *reinterpret_cast<const short8*>(
                &Vt[cur][(16 + c) * VSTR + (((kk * 4 + g) ^ (2 + cr3)) << 3)]);
            __builtin_amdgcn_s_setprio(1);
            oa00 = __builtin_amdgcn_mfma_f32_16x16x32_bf16(va0.s, pb0.s, oa00, 0, 0, 0);
            oa01 = __builtin_amdgcn_mfma_f32_16x16x32_bf16(va1.s, pb0.s, oa01, 0, 0, 0);
            oa10 = __builtin_amdgcn_mfma_f32_16x16x32_bf16(va0.s, pb1.s, oa10, 0, 0, 0);
            oa11 = __builtin_amdgcn_mfma_f32_16x16x32_bf16(va1.s, pb1.s, oa11, 0, 0, 0);
            __builtin_amdgcn_s_setprio(0);
        }

        if (more) STAGE_WRITE(cur ^ 1, nk0, nv0, nk1, nv1);   // write late
    }

    // final l reduce (deferred)
    ls0 += __shfl_xor(ls0, 16); ls0 += __shfl_xor(ls0, 32);
    ls1 += __shfl_xor(ls1, 16); ls1 += __shfl_xor(ls1, 32);

    const float i0 = 1.f / ls0, i1 = 1.f / ls1;
    const size_t item0 = ((size_t)split * 16 + bh) * NPIX + q0;
    const size_t item1 = ((size_t)split * 16 + bh) * NPIX + q1;
    uint32_t* d0 = reinterpret_cast<uint32_t*>(po + item0 * HD);
    d0[2 * g + 0] = cvtpk(oa00[0] * i0, oa00[1] * i0);
    d0[2 * g + 1] = cvtpk(oa00[2] * i0, oa00[3] * i0);
    d0[8 + 2 * g + 0] = cvtpk(oa01[0] * i0, oa01[1] * i0);
    d0[8 + 2 * g + 1] = cvtpk(oa01[2] * i0, oa01[3] * i0);
    uint32_t* d1 = reinterpret_cast<uint32_t*>(po + item1 * HD);
    d1[2 * g + 0] = cvtpk(oa10[0] * i1, oa10[1] * i1);
    d1[2 * g + 1] = cvtpk(oa10[2] * i1, oa10[3] * i1);
    d1[8 + 2 * g + 0] = cvtpk(oa11[0] * i1, oa11[1] * i1);
    d1[8 + 2 * g + 1] = cvtpk(oa11[2] * i1, oa11[3] * i1);
    if (g == 0) {
        pml[item0] = make_float2(m0, ls0);   // m in log2 domain
        pml[item1] = make_float2(m1, ls1);
    }
#undef STAGE_LOAD
#undef STAGE_WRITE
}

// ---------------- Combine split-K partials -> attn[:, 256:512) bf16 (log2 m)
__global__ __launch_bounds__(256)
void self_attn_combine(const uint16_t* __restrict__ po, const float2* __restrict__ pml,
                       uint16_t* __restrict__ attn)
{
    const int idx = blockIdx.x * 256 + threadIdx.x;
    const int d = idx & (HD - 1);
    const int q = (idx >> 5) % NPIX;
    const int bh = idx / (HD * NPIX);
    const int h = bh & (HEADS - 1);
    const int b = bh >> 3;

    float2 ml[KSPLIT];
    float M = -1e30f;
    #pragma unroll
    for (int s = 0; s < KSPLIT; ++s) {
        ml[s] = pml[((size_t)s * 16 + bh) * NPIX + q];
        M = fmaxf(M, ml[s].x);
    }
    float num = 0.f, den = 0.f;
    #pragma unroll
    for (int s = 0; s < KSPLIT; ++s) {
        const float w = ex2(ml[s].x - M) * ml[s].y;
        const float o = bf2f((uint32_t)po[(((size_t)s * 16 + bh) * NPIX + q) * HD + d]);
        num = fmaf(w, o, num);
        den += w;
    }
    attn[((size_t)b * NPIX + q) * DIMC + 256 + h * HD + d] = f2bf(num / den);
}

extern "C" void kernel_launch(void* const* d_in, const int* in_sizes, int n_in,
                              void* d_out, int out_size, void* d_ws, size_t ws_size,
                              hipStream_t stream)
{
    const float* x     = (const float*)d_in[0];
    const float* Wqkv  = (const float*)d_in[1];
    const float* bqkv  = (const float*)d_in[2];
    const float* rpb   = (const float*)d_in[3];
    const float* Wproj = (const float*)d_in[4];
    const float* bproj = (const float*)d_in[5];

    uint16_t* qkv  = (uint16_t*)d_ws;                     // [ROWS][C3]   14.2 MB
    uint16_t* attn = qkv + (size_t)ROWS * C3;             // [ROWS][DIMC]  4.7 MB
    uint16_t* wqt  = attn + (size_t)ROWS * DIMC;          // [C3][DIMC]    1.6 MB
    uint16_t* wpt  = wqt + (size_t)C3 * DIMC;             // [DIMC][DIMC]  0.5 MB
    float2*   pml  = (float2*)(wpt + (size_t)DIMC * DIMC);// 4*16*NPIX     1.2 MB
    uint16_t* po   = (uint16_t*)d_out;                    // partial scratch (dead until gemm2)

    const dim3 blk(256);
    transpose_to_bf16<<<dim3(DIMC / 32, C3 / 32), blk, 0, stream>>>(Wqkv, wqt, DIMC, C3);
    transpose_to_bf16<<<dim3(DIMC / 32, DIMC / 32), blk, 0, stream>>>(Wproj, wpt, DIMC, DIMC);
    gemm_mfma<true, false, true><<<dim3(C3 / 128, ROWS / 128), blk, 0, stream>>>(
        x, wqt, bqkv, qkv, ROWS, C3, DIMC);
    na_attn_mfma<<<dim3(BB * HEADS * 36), blk, 0, stream>>>(qkv, rpb, attn);
    self_attn_flash<<<dim3(16 * NQBLK * KSPLIT), blk, 0, stream>>>(qkv, po, pml);
    self_attn_combine<<<dim3((16 * NPIX * HD) / 256), blk, 0, stream>>>(po, pml, attn);
    gemm_mfma<false, true, false><<<dim3(DIMC / 128, ROWS / 128), blk, 0, stream>>>(
        attn, wpt, bproj, d_out, ROWS, DIMC, DIMC);
}

// Round 13
// 94.707 us; speedup vs baseline: 8.8740x; 1.1168x over previous
//
#include <hip/hip_runtime.h>
#include <cstdint>
#include <cstddef>

// MixedAttention: transpose-W -> MFMA qkv GEMM (fused f32->bf16, Q prescaled) ->
// {tile-MFMA na attn | MFMA flash self attn} -> MFMA proj GEMM.
// r13: flash shuffle-free P-repack via key permutation sigma (swap bits 4,5 of
// LDS K row index), paired-column Vt with b32 writes + XOR swizzle (VSTR=72).

#define DIMC 512
#define HEADS 8
#define HD 32
#define KSZ 7
#define HH 48
#define WW 48
#define BB 2
#define NPIX (HH * WW)         // 2304
#define ROWS (BB * NPIX)       // 4608
#define C3 (3 * DIMC)          // 1536
#define TK 64                  // flash key tile
#define KSPLIT 4
#define KCHUNK (NPIX / KSPLIT) // 576
#define NTILES (KCHUNK / TK)   // 9
#define QB 128                 // queries per block (32 per wave)
#define NQBLK (NPIX / QB)      // 18
#define ROWE 40                // K LDS row stride bf16 (80B)
#define VSTR 72                // flash Vt row stride bf16 (64 cols + 8 pad)
#define VROWE 232              // na Vt row stride
#define LOG2E 1.4426950408889634f

typedef __attribute__((ext_vector_type(8))) short short8;
typedef __attribute__((ext_vector_type(4))) float f32x4;
union frag8 { short8 s; uint32_t u[4]; };

static __device__ __forceinline__ float bf2f(uint32_t u) {
    return __builtin_bit_cast(float, u << 16);
}
static __device__ __forceinline__ uint16_t f2bf(float f) {
    uint32_t x = __builtin_bit_cast(uint32_t, f);
    uint32_t r = x + 0x7fffu + ((x >> 16) & 1u);
    return (uint16_t)(r >> 16);
}
static __device__ __forceinline__ uint32_t cvtpk(float lo, float hi) {
    uint32_t r;
    asm("v_cvt_pk_bf16_f32 %0, %1, %2" : "=v"(r) : "v"(lo), "v"(hi));
    return r;
}
static __device__ __forceinline__ float ex2(float x) {
    return __builtin_amdgcn_exp2f(x);
}

// ---------------- W[K][N] fp32 -> Wt[N][K] bf16
__global__ __launch_bounds__(256)
void transpose_to_bf16(const float* __restrict__ W, uint16_t* __restrict__ Wt,
                       int K, int N)
{
    __shared__ float tile[32][33];
    const int tx = threadIdx.x & 31, ty = threadIdx.x >> 5;
    const int k0 = blockIdx.x * 32, n0 = blockIdx.y * 32;
    #pragma unroll
    for (int i = 0; i < 4; ++i)
        tile[ty + 8 * i][tx] = W[(size_t)(k0 + ty + 8 * i) * N + n0 + tx];
    __syncthreads();
    #pragma unroll
    for (int i = 0; i < 4; ++i)
        Wt[(size_t)(n0 + ty + 8 * i) * K + k0 + tx] = f2bf(tile[tx][ty + 8 * i]);
}

// ---------------- MFMA GEMM: C[M,N] = A[M][K] * Bt_bf16[N][K]^T + bias
template<bool A_F32, bool OUT_F32, bool QSCALE>
__global__ __launch_bounds__(256)
void gemm_mfma(const void* __restrict__ Av, const uint16_t* __restrict__ Bt,
               const float* __restrict__ bias, void* __restrict__ Cv,
               int M, int N, int K)
{
    constexpr int BM = 128, BK = 32;
    constexpr float QSC = 0.17677669529663687f * LOG2E;
    __shared__ __align__(16) uint16_t Al[BM * ROWE];
    __shared__ __align__(16) uint16_t Bl[BM * ROWE];
    const int tid = threadIdx.x;
    const int lane = tid & 63, wv = tid >> 6;
    const int c = lane & 15, g = lane >> 4;
    const int wr = wv >> 1, wc = wv & 1;
    const int m0 = blockIdx.y * BM, n0 = blockIdx.x * BM;
    const int srow = tid >> 2, skc = (tid & 3) * 8;

    f32x4 acc[4][4];
    #pragma unroll
    for (int mi = 0; mi < 4; ++mi)
        #pragma unroll
        for (int ni = 0; ni < 4; ++ni)
            acc[mi][ni] = (f32x4){0.f, 0.f, 0.f, 0.f};

    for (int k0 = 0; k0 < K; k0 += BK) {
        __syncthreads();
        #pragma unroll
        for (int half = 0; half < 2; ++half) {
            const int row = srow + half * 64;
            if (A_F32) {
                const float* A32 = (const float*)Av;
                const float4 a0 = *reinterpret_cast<const float4*>(&A32[(size_t)(m0 + row) * K + k0 + skc]);
                const float4 a1 = *reinterpret_cast<const float4*>(&A32[(size_t)(m0 + row) * K + k0 + skc + 4]);
                *reinterpret_cast<uint4*>(&Al[row * ROWE + skc]) =
                    make_uint4(cvtpk(a0.x, a0.y), cvtpk(a0.z, a0.w),
                               cvtpk(a1.x, a1.y), cvtpk(a1.z, a1.w));
            } else {
                const uint16_t* A16 = (const uint16_t*)Av;
                *reinterpret_cast<uint4*>(&Al[row * ROWE + skc]) =
                    *reinterpret_cast<const uint4*>(&A16[(size_t)(m0 + row) * K + k0 + skc]);
            }
            *reinterpret_cast<uint4*>(&Bl[row * ROWE + skc]) =
                *reinterpret_cast<const uint4*>(&Bt[(size_t)(n0 + row) * K + k0 + skc]);
        }
        __syncthreads();

        frag8 a[4], b[4];
        #pragma unroll
        for (int mi = 0; mi < 4; ++mi)
            a[mi].s = *reinterpret_cast<const short8*>(&Al[(wr * 64 + mi * 16 + c) * ROWE + g * 8]);
        #pragma unroll
        for (int ni = 0; ni < 4; ++ni)
            b[ni].s = *reinterpret_cast<const short8*>(&Bl[(wc * 64 + ni * 16 + c) * ROWE + g * 8]);
        #pragma unroll
        for (int mi = 0; mi < 4; ++mi)
            #pragma unroll
            for (int ni = 0; ni < 4; ++ni)
                acc[mi][ni] = __builtin_amdgcn_mfma_f32_16x16x32_bf16(
                    a[mi].s, b[ni].s, acc[mi][ni], 0, 0, 0);
    }

    #pragma unroll
    for (int mi = 0; mi < 4; ++mi) {
        #pragma unroll
        for (int ni = 0; ni < 4; ++ni) {
            const int row = m0 + wr * 64 + mi * 16 + 4 * g;
            const int col = n0 + wc * 64 + ni * 16 + c;
            const float bv = bias[col];
            float f = 1.f;
            if (QSCALE) f = (col < 256 || (col >= 768 && col < 1024)) ? QSC : 1.f;
            #pragma unroll
            for (int r = 0; r < 4; ++r) {
                const float val = (acc[mi][ni][r] + bv) * f;
                if (OUT_F32)
                    ((float*)Cv)[(size_t)(row + r) * N + col] = val;
                else
                    ((uint16_t*)Cv)[(size_t)(row + r) * N + col] = f2bf(val);
            }
        }
    }
}

// ---------------- Tile-MFMA neighborhood attention (unchanged from r12)
__global__ __launch_bounds__(256)
void na_attn_mfma(const uint16_t* __restrict__ qkv, const float* __restrict__ rpb,
                  uint16_t* __restrict__ attn)
{
    const int tid = threadIdx.x;
    const int lane = tid & 63, wv = tid >> 6;
    const int c = lane & 15, g = lane >> 4, g4 = g * 4;
    const int bid = blockIdx.x;
    const int tile = bid % 36;
    const int bh = bid / 36;
    const int h = bh & (HEADS - 1), b = bh >> 3;
    const int t0i = (tile / 6) * 8, t0j = (tile % 6) * 8;
    const int u0i = min(max(t0i - 3, 0), HH - 14);
    const int u0j = min(max(t0j - 3, 0), WW - 14);
    const size_t rowbase = (size_t)b * NPIX;

    __shared__ __align__(16) uint16_t K_l[224 * ROWE];
    __shared__ __align__(16) uint16_t Vt[32 * VROWE];
    __shared__ float rpb_l[169];

    if (tid < 169) rpb_l[tid] = rpb[h * 169 + tid] * LOG2E;
    #pragma unroll
    for (int it = 0; it < 4; ++it) {
        const int idx = it * 256 + tid;
        if (idx < 896) {
            const int u = idx >> 2, dc = idx & 3;
            const int uc = u & 15, ur = u >> 4;
            if (uc < 14) {
                const int grow = (u0i + ur) * WW + (u0j + uc);
                const uint16_t* src = qkv + (rowbase + grow) * C3 + 256 + h * HD + dc * 8;
                *reinterpret_cast<uint4*>(&K_l[u * ROWE + dc * 8]) =
                    *reinterpret_cast<const uint4*>(src);
                const uint4 vw = *reinterpret_cast<const uint4*>(src + 256);
                const uint16_t* vh = reinterpret_cast<const uint16_t*>(&vw);
                #pragma unroll
                for (int i = 0; i < 8; ++i)
                    Vt[(dc * 8 + i) * VROWE + u] = vh[i];
            } else {
                *reinterpret_cast<uint4*>(&K_l[u * ROWE + dc * 8]) = make_uint4(0, 0, 0, 0);
                #pragma unroll
                for (int i = 0; i < 8; ++i)
                    Vt[(dc * 8 + i) * VROWE + u] = 0;
            }
        }
    }

    const int qid = wv * 16 + c;
    const int qi = t0i + (qid >> 3), qj = t0j + (qid & 7);
    const int pixq = qi * WW + qj;
    const int niq = min(max(qi - 3, 0), HH - KSZ);
    const int njq = min(max(qj - 3, 0), WW - KSZ);
    const int piq = 3 + max(3 - qi, 0) + ((qi + 3 >= HH) ? (HH - qi - 4) : 0);
    const int pjq = 3 + max(3 - qj, 0) + ((qj + 3 >= WW) ? (WW - qj - 4) : 0);
    const int ni_rel = niq - u0i, nj_rel = njq - u0j;
    const int bb = (piq - ni_rel) * 13 + (pjq - nj_rel);

    frag8 qf;
    qf.s = *reinterpret_cast<const short8*>(qkv + (rowbase + pixq) * C3 + h * HD + g * 8);

    __syncthreads();

    float pex[14][4];
    float m = -1e30f;
    #pragma unroll
    for (int f = 0; f < 14; ++f) {
        frag8 ka;
        ka.s = *reinterpret_cast<const short8*>(&K_l[(16 * f + c) * ROWE + g * 8]);
        f32x4 s = {0.f, 0.f, 0.f, 0.f};
        s = __builtin_amdgcn_mfma_f32_16x16x32_bf16(ka.s, qf.s, s, 0, 0, 0);
        const bool rok = (unsigned)(f - ni_rel) < 7u;
        #pragma unroll
        for (int r = 0; r < 4; ++r) {
            const int uc = g4 + r;
            const bool ok = rok && ((unsigned)(uc - nj_rel) < 7u);
            const int addr = ok ? (bb + 13 * f + uc) : 0;
            const float v = s[r] + rpb_l[addr];
            pex[f][r] = ok ? v : -1e30f;
            m = fmaxf(m, pex[f][r]);
        }
    }
    m = fmaxf(m, __shfl_xor(m, 16));
    m = fmaxf(m, __shfl_xor(m, 32));
    float l = 0.f;
    #pragma unroll
    for (int f = 0; f < 14; ++f)
        #pragma unroll
        for (int r = 0; r < 4; ++r) {
            pex[f][r] = ex2(pex[f][r] - m);
            l += pex[f][r];
        }
    l += __shfl_xor(l, 16);
    l += __shfl_xor(l, 32);

    f32x4 of0 = {0.f, 0.f, 0.f, 0.f}, of1 = {0.f, 0.f, 0.f, 0.f};
    const int sbase = (g & 1) * 32 + c;
    #pragma unroll
    for (int kk = 0; kk < 7; ++kk) {
        uint32_t pk0[2], pk1[2];
        pk0[0] = cvtpk(pex[2 * kk][0], pex[2 * kk][1]);
        pk0[1] = cvtpk(pex[2 * kk][2], pex[2 * kk][3]);
        pk1[0] = cvtpk(pex[2 * kk + 1][0], pex[2 * kk + 1][1]);
        pk1[1] = cvtpk(pex[2 * kk + 1][2], pex[2 * kk + 1][3]);
        frag8 pb;
        #pragma unroll
        for (int tt = 0; tt < 4; ++tt) {
            const int srcLane = sbase + ((tt >> 1) << 4);
            const uint32_t v0 = __shfl(pk0[tt & 1], srcLane);
            const uint32_t v1 = __shfl(pk1[tt & 1], srcLane);
            pb.u[tt] = (g >= 2) ? v1 : v0;
        }
        frag8 va0, va1;
        va0.s = *reinterpret_cast<const short8*>(&Vt[c * VROWE + kk * 32 + g * 8]);
        va1.s = *reinterpret_cast<const short8*>(&Vt[(16 + c) * VROWE + kk * 32 + g * 8]);
        of0 = __builtin_amdgcn_mfma_f32_16x16x32_bf16(va0.s, pb.s, of0, 0, 0, 0);
        of1 = __builtin_amdgcn_mfma_f32_16x16x32_bf16(va1.s, pb.s, of1, 0, 0, 0);
    }

    const float invl = 1.f / l;
    uint32_t* dst = reinterpret_cast<uint32_t*>(attn + (rowbase + pixq) * DIMC + h * HD);
    dst[2 * g + 0] = cvtpk(of0[0] * invl, of0[1] * invl);
    dst[2 * g + 1] = cvtpk(of0[2] * invl, of0[3] * invl);
    dst[8 + 2 * g + 0] = cvtpk(of1[0] * invl, of1[1] * invl);
    dst[8 + 2 * g + 1] = cvtpk(of1[2] * invl, of1[3] * invl);
}

// ---------------- MFMA flash self-attention v6: shuffle-free P repack.
// K LDS row i holds physical key sigma(i) = swap bits 4,5 of i.
// Vt column 2s+d holds key s+32d (pair layout), XOR-swizzled, b32 writes.
// => PV B-operand u[tt] = cvtpk(sc[2kk][tt], sc[2kk+1][tt]) lane-local.
__global__ __launch_bounds__(256)
void self_attn_flash(const uint16_t* __restrict__ qkv,
                     uint16_t* __restrict__ po, float2* __restrict__ pml)
{
    const int tid = threadIdx.x;
    const int lane = tid & 63, wv = tid >> 6;
    const int c = lane & 15, g = lane >> 4;
    const int bid = blockIdx.x;               // [bh][qblk][split]
    const int split = bid & (KSPLIT - 1);
    const int qblk = (bid >> 2) % NQBLK;
    const int bh = bid / (KSPLIT * NQBLK);
    const int h = bh & (HEADS - 1);
    const int b = bh >> 3;
    const size_t rowbase = (size_t)b * NPIX;
    const int qbase = qblk * QB + wv * 32;
    const int q0 = qbase + c, q1 = qbase + 16 + c;

    __shared__ __align__(16) uint16_t Ks[2][TK * ROWE];      // 64 keys x 32d (sigma order)
    __shared__ __align__(16) uint16_t Vt[2][32 * VSTR];      // 32d x 64 cols (paired)

    frag8 qf0, qf1;   // Q prescaled by scale*log2e in gemm1
    qf0.s = *reinterpret_cast<const short8*>(qkv + (rowbase + q0) * C3 + 768 + h * HD + g * 8);
    qf1.s = *reinterpret_cast<const short8*>(qkv + (rowbase + q1) * C3 + 768 + h * HD + g * 8);

    float m0 = -1e30f, m1 = -1e30f, ls0 = 0.f, ls1 = 0.f;
    f32x4 oa00 = {0,0,0,0}, oa01 = {0,0,0,0};
    f32x4 oa10 = {0,0,0,0}, oa11 = {0,0,0,0};

    // staging decompositions
    const int skk = tid >> 2, kd = (tid & 3) * 8;                     // K: 1 key, 16B
    const int sgk = (skk & 15) | ((skk & 16) << 1) | ((skk & 32) >> 1); // sigma
    const int skv = tid >> 3, sdc = tid & 7;                          // V: keys skv, skv+32
    const int cp2 = 2 * (skv ^ ((sdc >> 1) << 3));                    // swizzled col base

    uint4 KW; uint2 VA, VB;
#define STAGE_LOAD(T) do {                                                            \
    const size_t _tb = rowbase + split * KCHUNK + (T) * TK;                           \
    KW = *reinterpret_cast<const uint4*>(qkv + (_tb + sgk) * C3 + 1024 + h * HD + kd);\
    const uint16_t* _vp = qkv + (_tb + skv) * C3 + 1280 + h * HD + sdc * 4;           \
    VA = *reinterpret_cast<const uint2*>(_vp);                                        \
    VB = *reinterpret_cast<const uint2*>(_vp + 32 * C3); } while (0)

#define STAGE_WRITE(BUF) do {                                                         \
    *reinterpret_cast<uint4*>(&Ks[BUF][skk * ROWE + kd]) = KW;                        \
    const uint32_t _pa[4] = {VA.x & 0xffffu, VA.x >> 16, VA.y & 0xffffu, VA.y >> 16}; \
    const uint32_t _pb[4] = {VB.x & 0xffffu, VB.x >> 16, VB.y & 0xffffu, VB.y >> 16}; \
    _Pragma("unroll")                                                                 \
    for (int _i = 0; _i < 4; ++_i)                                                    \
        *reinterpret_cast<uint32_t*>(&Vt[BUF][(sdc * 4 + _i) * VSTR + cp2]) =         \
            _pa[_i] | (_pb[_i] << 16); } while (0)

    STAGE_LOAD(0);
    STAGE_WRITE(0);

    const int x0 = (c >> 3) << 3;          // pair-XOR for row c
    const int x1 = 16 + x0;                // pair-XOR for row 16+c

    for (int t = 0; t < NTILES; ++t) {
        __syncthreads();

        const bool more = (t + 1 < NTILES);
        if (more) STAGE_LOAD(t + 1);       // T14: issue early

        const int cur = t & 1;
        frag8 ka0, ka1, ka2, ka3;
        ka0.s = *reinterpret_cast<const short8*>(&Ks[cur][c * ROWE + g * 8]);
        ka1.s = *reinterpret_cast<const short8*>(&Ks[cur][(16 + c) * ROWE + g * 8]);
        ka2.s = *reinterpret_cast<const short8*>(&Ks[cur][(32 + c) * ROWE + g * 8]);
        ka3.s = *reinterpret_cast<const short8*>(&Ks[cur][(48 + c) * ROWE + g * 8]);
        f32x4 sc0[4], sc1[4];
        #pragma unroll
        for (int kf = 0; kf < 4; ++kf) {
            sc0[kf] = (f32x4){0,0,0,0};
            sc1[kf] = (f32x4){0,0,0,0};
        }
        __builtin_amdgcn_s_setprio(1);
        sc0[0] = __builtin_amdgcn_mfma_f32_16x16x32_bf16(ka0.s, qf0.s, sc0[0], 0, 0, 0);
        sc0[1] = __builtin_amdgcn_mfma_f32_16x16x32_bf16(ka1.s, qf0.s, sc0[1], 0, 0, 0);
        sc0[2] = __builtin_amdgcn_mfma_f32_16x16x32_bf16(ka2.s, qf0.s, sc0[2], 0, 0, 0);
        sc0[3] = __builtin_amdgcn_mfma_f32_16x16x32_bf16(ka3.s, qf0.s, sc0[3], 0, 0, 0);
        sc1[0] = __builtin_amdgcn_mfma_f32_16x16x32_bf16(ka0.s, qf1.s, sc1[0], 0, 0, 0);
        sc1[1] = __builtin_amdgcn_mfma_f32_16x16x32_bf16(ka1.s, qf1.s, sc1[1], 0, 0, 0);
        sc1[2] = __builtin_amdgcn_mfma_f32_16x16x32_bf16(ka2.s, qf1.s, sc1[2], 0, 0, 0);
        sc1[3] = __builtin_amdgcn_mfma_f32_16x16x32_bf16(ka3.s, qf1.s, sc1[3], 0, 0, 0);
        __builtin_amdgcn_s_setprio(0);

        float t0 = sc0[0][0], t1 = sc1[0][0];
        #pragma unroll
        for (int kf = 0; kf < 4; ++kf)
            #pragma unroll
            for (int r = 0; r < 4; ++r) {
                t0 = fmaxf(t0, sc0[kf][r]);
                t1 = fmaxf(t1, sc1[kf][r]);
            }
        t0 = fmaxf(t0, __shfl_xor(t0, 16)); t0 = fmaxf(t0, __shfl_xor(t0, 32));
        t1 = fmaxf(t1, __shfl_xor(t1, 16)); t1 = fmaxf(t1, __shfl_xor(t1, 32));

        const int ok = (t0 - m0 <= 11.54f) && (t1 - m1 <= 11.54f);
        if (!__all(ok)) {
            const float nm0 = fmaxf(m0, t0), nm1 = fmaxf(m1, t1);
            const float c0 = ex2(m0 - nm0), c1 = ex2(m1 - nm1);
            ls0 *= c0; ls1 *= c1;
            oa00 *= c0; oa01 *= c0; oa10 *= c1; oa11 *= c1;
            m0 = nm0; m1 = nm1;
        }

        #pragma unroll
        for (int kf = 0; kf < 4; ++kf)
            #pragma unroll
            for (int r = 0; r < 4; ++r) {
                sc0[kf][r] = ex2(sc0[kf][r] - m0); ls0 += sc0[kf][r];
                sc1[kf][r] = ex2(sc1[kf][r] - m1); ls1 += sc1[kf][r];
            }

        // PV: shuffle-free B operand (sigma + paired Vt)
        #pragma unroll
        for (int kk = 0; kk < 2; ++kk) {
            frag8 pb0, pb1;
            #pragma unroll
            for (int tt = 0; tt < 4; ++tt) {
                pb0.u[tt] = cvtpk(sc0[2 * kk][tt], sc0[2 * kk + 1][tt]);
                pb1.u[tt] = cvtpk(sc1[2 * kk][tt], sc1[2 * kk + 1][tt]);
            }
            const int p0 = 16 * kk + 4 * g;
            frag8 va0, va1;
            va0.s = *reinterpret_cast<const short8*>(&Vt[cur][c * VSTR + 2 * (p0 ^ x0)]);
            va1.s = *reinterpret_cast<const short8*>(&Vt[cur][(16 + c) * VSTR + 2 * (p0 ^ x1)]);
            __builtin_amdgcn_s_setprio(1);
            oa00 = __builtin_amdgcn_mfma_f32_16x16x32_bf16(va0.s, pb0.s, oa00, 0, 0, 0);
            oa01 = __builtin_amdgcn_mfma_f32_16x16x32_bf16(va1.s, pb0.s, oa01, 0, 0, 0);
            oa10 = __builtin_amdgcn_mfma_f32_16x16x32_bf16(va0.s, pb1.s, oa10, 0, 0, 0);
            oa11 = __builtin_amdgcn_mfma_f32_16x16x32_bf16(va1.s, pb1.s, oa11, 0, 0, 0);
            __builtin_amdgcn_s_setprio(0);
        }

        if (more) STAGE_WRITE(cur ^ 1);    // write late
    }

    ls0 += __shfl_xor(ls0, 16); ls0 += __shfl_xor(ls0, 32);
    ls1 += __shfl_xor(ls1, 16); ls1 += __shfl_xor(ls1, 32);

    const float i0 = 1.f / ls0, i1 = 1.f / ls1;
    const size_t item0 = ((size_t)split * 16 + bh) * NPIX + q0;
    const size_t item1 = ((size_t)split * 16 + bh) * NPIX + q1;
    uint32_t* d0 = reinterpret_cast<uint32_t*>(po + item0 * HD);
    d0[2 * g + 0] = cvtpk(oa00[0] * i0, oa00[1] * i0);
    d0[2 * g + 1] = cvtpk(oa00[2] * i0, oa00[3] * i0);
    d0[8 + 2 * g + 0] = cvtpk(oa01[0] * i0, oa01[1] * i0);
    d0[8 + 2 * g + 1] = cvtpk(oa01[2] * i0, oa01[3] * i0);
    uint32_t* d1 = reinterpret_cast<uint32_t*>(po + item1 * HD);
    d1[2 * g + 0] = cvtpk(oa10[0] * i1, oa10[1] * i1);
    d1[2 * g + 1] = cvtpk(oa10[2] * i1, oa10[3] * i1);
    d1[8 + 2 * g + 0] = cvtpk(oa11[0] * i1, oa11[1] * i1);
    d1[8 + 2 * g + 1] = cvtpk(oa11[2] * i1, oa11[3] * i1);
    if (g == 0) {
        pml[item0] = make_float2(m0, ls0);   // m in log2 domain
        pml[item1] = make_float2(m1, ls1);
    }
#undef STAGE_LOAD
#undef STAGE_WRITE
}

// ---------------- Combine split-K partials -> attn[:, 256:512) bf16 (log2 m)
__global__ __launch_bounds__(256)
void self_attn_combine(const uint16_t* __restrict__ po, const float2* __restrict__ pml,
                       uint16_t* __restrict__ attn)
{
    const int idx = blockIdx.x * 256 + threadIdx.x;
    const int d = idx & (HD - 1);
    const int q = (idx >> 5) % NPIX;
    const int bh = idx / (HD * NPIX);
    const int h = bh & (HEADS - 1);
    const int b = bh >> 3;

    float2 ml[KSPLIT];
    float M = -1e30f;
    #pragma unroll
    for (int s = 0; s < KSPLIT; ++s) {
        ml[s] = pml[((size_t)s * 16 + bh) * NPIX + q];
        M = fmaxf(M, ml[s].x);
    }
    float num = 0.f, den = 0.f;
    #pragma unroll
    for (int s = 0; s < KSPLIT; ++s) {
        const float w = ex2(ml[s].x - M) * ml[s].y;
        const float o = bf2f((uint32_t)po[(((size_t)s * 16 + bh) * NPIX + q) * HD + d]);
        num = fmaf(w, o, num);
        den += w;
    }
    attn[((size_t)b * NPIX + q) * DIMC + 256 + h * HD + d] = f2bf(num / den);
}

extern "C" void kernel_launch(void* const* d_in, const int* in_sizes, int n_in,
                              void* d_out, int out_size, void* d_ws, size_t ws_size,
                              hipStream_t stream)
{
    const float* x     = (const float*)d_in[0];
    const float* Wqkv  = (const float*)d_in[1];
    const float* bqkv  = (const float*)d_in[2];
    const float* rpb   = (const float*)d_in[3];
    const float* Wproj = (const float*)d_in[4];
    const float* bproj = (const float*)d_in[5];

    uint16_t* qkv  = (uint16_t*)d_ws;                     // [ROWS][C3]   14.2 MB
    uint16_t* attn = qkv + (size_t)ROWS * C3;             // [ROWS][DIMC]  4.7 MB
    uint16_t* wqt  = attn + (size_t)ROWS * DIMC;          // [C3][DIMC]    1.6 MB
    uint16_t* wpt  = wqt + (size_t)C3 * DIMC;             // [DIMC][DIMC]  0.5 MB
    float2*   pml  = (float2*)(wpt + (size_t)DIMC * DIMC);// 4*16*NPIX     1.2 MB
    uint16_t* po   = (uint16_t*)d_out;                    // partial scratch (dead until gemm2)

    const dim3 blk(256);
    transpose_to_bf16<<<dim3(DIMC / 32, C3 / 32), blk, 0, stream>>>(Wqkv, wqt, DIMC, C3);
    transpose_to_bf16<<<dim3(DIMC / 32, DIMC / 32), blk, 0, stream>>>(Wproj, wpt, DIMC, DIMC);
    gemm_mfma<true, false, true><<<dim3(C3 / 128, ROWS / 128), blk, 0, stream>>>(
        x, wqt, bqkv, qkv, ROWS, C3, DIMC);
    na_attn_mfma<<<dim3(BB * HEADS * 36), blk, 0, stream>>>(qkv, rpb, attn);
    self_attn_flash<<<dim3(16 * NQBLK * KSPLIT), blk, 0, stream>>>(qkv, po, pml);
    self_attn_combine<<<dim3((16 * NPIX * HD) / 256), blk, 0, stream>>>(po, pml, attn);
    gemm_mfma<false, true, false><<<dim3(DIMC / 128, ROWS / 128), blk, 0, stream>>>(
        attn, wpt, bproj, d_out, ROWS, DIMC, DIMC);
}